// Round 12
// baseline (103.457 us; speedup 1.0000x reference)
//
#include <hip/hip_runtime.h>
#include <stdint.h>

typedef __bf16 bf16;
typedef __bf16 bf16x8 __attribute__((ext_vector_type(8)));
typedef __bf16 bf16x4 __attribute__((ext_vector_type(4)));
typedef float f32x4 __attribute__((ext_vector_type(4)));
typedef float f32x16 __attribute__((ext_vector_type(16)));
typedef uint32_t u32x4 __attribute__((ext_vector_type(4)));

#define MFMA16x16x32(A, B, C) __builtin_amdgcn_mfma_f32_16x16x32_bf16((A), (B), (C), 0, 0, 0)
#define MFMA32x32x16(A, B, C) __builtin_amdgcn_mfma_f32_32x32x16_bf16((A), (B), (C), 0, 0, 0)
#define SBAR() do { __builtin_amdgcn_s_barrier(); __builtin_amdgcn_sched_barrier(0); } while (0)

__device__ __forceinline__ void gload_lds16(const void* g, void* l) {
  __builtin_amdgcn_global_load_lds((const __attribute__((address_space(1))) void*)g,
                                   (__attribute__((address_space(3))) void*)l,
                                   16, 0, 0);
}

__device__ __forceinline__ float fexp2(float x) { return __builtin_amdgcn_exp2f(x); }

__device__ __forceinline__ uint32_t cvtpk(float a, float b) {
  uint32_t r;
  asm("v_cvt_pk_bf16_f32 %0, %1, %2" : "=v"(r) : "v"(a), "v"(b));
  return r;
}
__device__ __forceinline__ void plswap(uint32_t& a, uint32_t& b) {
  asm volatile("v_permlane32_swap_b32 %0, %1" : "+v"(a), "+v"(b));
}

__device__ __forceinline__ bf16x8 cvt8(float4 a, float4 b) {
  bf16x8 o;
  o[0] = (bf16)a.x; o[1] = (bf16)a.y; o[2] = (bf16)a.z; o[3] = (bf16)a.w;
  o[4] = (bf16)b.x; o[5] = (bf16)b.y; o[6] = (bf16)b.z; o[7] = (bf16)b.w;
  return o;
}

// ---------------- inputs + weights -> bf16 (contiguous dst) ----------------
// layout: x1(4.19M) | x2(4.19M) | Wq | Wk | Wv | Wo (262144 each) = 9,437,184 elems
__global__ void cast_x(const float* __restrict__ x1, const float* __restrict__ x2,
                       const float* __restrict__ Wq, const float* __restrict__ Wk,
                       const float* __restrict__ Wv, const float* __restrict__ Wo,
                       bf16* __restrict__ out) {
  const size_t i = ((size_t)blockIdx.x * blockDim.x + threadIdx.x) * 8;
  const float* src;
  if      (i < 4194304u) src = x1 + i;
  else if (i < 8388608u) src = x2 + (i - 4194304u);
  else if (i < 8650752u) src = Wq + (i - 8388608u);
  else if (i < 8912896u) src = Wk + (i - 8650752u);
  else if (i < 9175040u) src = Wv + (i - 8912896u);
  else                   src = Wo + (i - 9175040u);
  float4 a = *reinterpret_cast<const float4*>(src);
  float4 b = *reinterpret_cast<const float4*>(src + 4);
  *reinterpret_cast<bf16x8*>(out + i) = cvt8(a, b);
}

// ---------------- QKV projection: 128x128 tile, all-bf16, ring-3, counted vmcnt -------
// grid (64, 12): bn<4 -> Q (x1b, *0.125*log2e), bn<8 -> K (x2b), else V^T (x2b).
// Per iter: 8 ds_read_b128 feed 16 MFMA; 4 glds/wave/tile, steady-state vmcnt(4).
__global__ __launch_bounds__(256, 3) void qkv128_kernel(
    const bf16* __restrict__ x1b, const bf16* __restrict__ x2b,
    const bf16* __restrict__ Wb, bf16* __restrict__ Qw,
    bf16* __restrict__ Kw, bf16* __restrict__ Vtw) {
  __shared__ bf16 As[3][128 * 32];
  __shared__ bf16 Bs[3][128 * 32];
  const int tid = threadIdx.x;
  const int w = tid >> 6, l = tid & 63;
  const int wr = w >> 1, wc = w & 1;
  const int lr = l & 15, lg = l >> 4;
  const int bm = blockIdx.x, bn = blockIdx.y;
  const int K = 512;
  const int sel = bn >> 2, wn = bn & 3;

  const bf16* A = (sel == 0) ? x1b : x2b;
  const bf16* B = Wb + (size_t)sel * 262144 + (size_t)wn * 128 * K;

  const int c_row = l >> 2;
  const int sw = ((l & 3) ^ (c_row & 3)) * 8;

  auto stage = [&](int t, int bb) {
#pragma unroll
    for (int i = 0; i < 2; i++) {
      const int q = w + i * 4;
      gload_lds16(A + (size_t)(bm * 128 + q * 16 + c_row) * K + t * 32 + sw, &As[bb][q * 512]);
      gload_lds16(B + (size_t)(q * 16 + c_row) * K + t * 32 + sw, &Bs[bb][q * 512]);
    }
  };

  f32x4 acc[4][4] = {};
  const int swz = (lr & 3) * 8;

  stage(0, 0);
  stage(1, 1);
  asm volatile("s_waitcnt vmcnt(4)" ::: "memory");
  SBAR();

  const int NT = 16;
  for (int t = 0; t < NT; t++) {
    if (t + 2 < NT) stage(t + 2, (t + 2) % 3);
    const int cur = t % 3;
    bf16x8 a[4], b[4];
#pragma unroll
    for (int mi = 0; mi < 4; mi++)
      a[mi] = *reinterpret_cast<const bf16x8*>(
          &As[cur][(wr * 64 + mi * 16 + lr) * 32 + (lg * 8 ^ swz)]);
#pragma unroll
    for (int ni = 0; ni < 4; ni++)
      b[ni] = *reinterpret_cast<const bf16x8*>(
          &Bs[cur][(wc * 64 + ni * 16 + lr) * 32 + (lg * 8 ^ swz)]);
#pragma unroll
    for (int mi = 0; mi < 4; mi++)
#pragma unroll
      for (int ni = 0; ni < 4; ni++)
        acc[mi][ni] = MFMA16x16x32(a[mi], b[ni], acc[mi][ni]);

    if (t + 1 < NT) {
      if (t + 2 < NT) asm volatile("s_waitcnt vmcnt(4)" ::: "memory");
      else            asm volatile("s_waitcnt vmcnt(0)" ::: "memory");
      asm volatile("s_waitcnt lgkmcnt(0)" ::: "memory");
      SBAR();
    }
  }

  // epilogue: C/D col=lane&15, row=(lane>>4)*4+reg
  const float scale = (sel == 0) ? 0.18033688011112f : 1.0f;
#pragma unroll
  for (int mi = 0; mi < 4; mi++) {
    const int m0 = bm * 128 + wr * 64 + mi * 16 + lg * 4;
#pragma unroll
    for (int ni = 0; ni < 4; ni++) {
      const int gn = wn * 128 + wc * 64 + ni * 16 + lr;  // h*64+d
      if (sel < 2) {
        bf16* dst = (sel == 0) ? Qw : Kw;
#pragma unroll
        for (int r = 0; r < 4; r++) {
          const int m = m0 + r;
          size_t d = (size_t)((m >> 11) * 8 + (gn >> 6)) * 131072 + (size_t)(m & 2047) * 64 + (gn & 63);
          dst[d] = (bf16)(acc[mi][ni][r] * scale);
        }
      } else {
        bf16x4 pv;
#pragma unroll
        for (int r = 0; r < 4; r++) pv[r] = (bf16)acc[mi][ni][r];
        size_t base = ((size_t)(m0 >> 11) * 512 + gn) * 2048 + (m0 & 2047);
        *reinterpret_cast<bf16x4*>(Vtw + base) = pv;
      }
    }
  }
}

// ---------------- out projection: C = AO @ Wo^T + bo (unchanged, validated) ----------
__global__ __launch_bounds__(256, 4) void outproj_kernel(
    const bf16* __restrict__ A0, const float* __restrict__ W0,
    float* __restrict__ C0, const float* __restrict__ bias) {
  __shared__ bf16 As[3][128 * 32];
  __shared__ bf16 Bs[2][64 * 32];
  const int tid = threadIdx.x;
  const int w = tid >> 6, l = tid & 63;
  const int wr = w >> 1, wc = w & 1;
  const int lr = l & 15, lg = l >> 4;
  const int bm = blockIdx.x, bn = blockIdx.y;
  const int K = 512;

  const float* Bf = W0 + (size_t)bn * 64 * K;
  const int c_row = l >> 2;
  const int c_s = l & 3;
  const int sw = (c_s ^ (c_row & 3)) * 8;

  float4 lb[2][2];
  auto issue_A = [&](int t, int bb) {
#pragma unroll
    for (int i = 0; i < 2; i++) {
      const int q = w + i * 4;
      gload_lds16(A0 + (size_t)(bm * 128 + q * 16 + c_row) * K + t * 32 + sw, &As[bb][q * 512]);
    }
  };
  auto issue_B = [&](int t, int s) {
    const float* pb = Bf + (size_t)(w * 16 + c_row) * K + t * 32 + c_s * 8;
    lb[s][0] = *reinterpret_cast<const float4*>(pb);
    lb[s][1] = *reinterpret_cast<const float4*>(pb + 4);
  };
  auto commit_B = [&](int s, int bb) {
    *reinterpret_cast<bf16x8*>(&Bs[bb][w * 512 + c_row * 32 + sw]) = cvt8(lb[s][0], lb[s][1]);
  };

  f32x4 acc[4][2] = {};
  const int swz = (lr & 3) * 8;

  issue_A(0, 0); issue_B(0, 0);
  issue_A(1, 1); issue_B(1, 1);
  asm volatile("s_waitcnt vmcnt(4)" ::: "memory");
  commit_B(0, 0);
  asm volatile("s_waitcnt lgkmcnt(0)" ::: "memory");
  SBAR();

  const int NT = 16;
  for (int t = 0; t < NT; t++) {
    if (t + 2 < NT) { issue_A(t + 2, (t + 2) % 3); issue_B(t + 2, t & 1); }

    bf16x8 a[4], b[2];
    const int cur = t % 3;
#pragma unroll
    for (int mi = 0; mi < 4; mi++)
      a[mi] = *reinterpret_cast<const bf16x8*>(
          &As[cur][(wr * 64 + mi * 16 + lr) * 32 + (lg * 8 ^ swz)]);
#pragma unroll
    for (int ni = 0; ni < 2; ni++)
      b[ni] = *reinterpret_cast<const bf16x8*>(
          &Bs[t & 1][(wc * 32 + ni * 16 + lr) * 32 + (lg * 8 ^ swz)]);
#pragma unroll
    for (int mi = 0; mi < 4; mi++)
#pragma unroll
      for (int ni = 0; ni < 2; ni++)
        acc[mi][ni] = MFMA16x16x32(a[mi], b[ni], acc[mi][ni]);

    if (t + 1 < NT) {
      if (t + 2 < NT) asm volatile("s_waitcnt vmcnt(4)" ::: "memory");
      else            asm volatile("s_waitcnt vmcnt(0)" ::: "memory");
      commit_B((t + 1) & 1, (t + 1) & 1);
      asm volatile("s_waitcnt lgkmcnt(0)" ::: "memory");
      SBAR();
    }
  }

#pragma unroll
  for (int mi = 0; mi < 4; mi++) {
    const int m0 = bm * 128 + wr * 64 + mi * 16 + lg * 4;
#pragma unroll
    for (int ni = 0; ni < 2; ni++) {
      const int gn = bn * 64 + wc * 32 + ni * 16 + lr;
      const float bv = bias[gn];
#pragma unroll
      for (int r = 0; r < 4; r++)
        C0[(size_t)(m0 + r) * 512 + gn] = acc[mi][ni][r] + bv;
    }
  }
}

// ---------------- flash attention: 32x32 in-reg P, kv-split, 4 blocks/CU -------------
// Block: 256 thr = 4 waves = 2 q-groups x 2 kv-halves; 64 q/block; grid 1024.
// KVBLK=64, 2-ring LDS (32KB/block -> 4 blocks/CU = 16 waves/CU = 4/SIMD).
// Wave (qg,kvh): QK S^T for 32 kv x 32 q (1 chain of 4 MFMA), lane-local softmax,
// cvt_pk+permlane P-frags, PV partial over its kv-half. O combined once via dead LDS.
__global__ __launch_bounds__(256, 4) void attn_kernel(
    const bf16* __restrict__ Q, const bf16* __restrict__ Kk,
    const bf16* __restrict__ Vt, bf16* __restrict__ AO) {
  __shared__ bf16 Kb2[2][64 * 64];  // 16KB
  __shared__ bf16 Vb2[2][64 * 64];  // 16KB

  const int tid = threadIdx.x;
  const int w = tid >> 6, l = tid & 63;
  const int q32 = l & 31;
  const int h = l >> 5;
  const int qg = w >> 1, kvh = w & 1;

  // XCD-aware decode: grid 1024, lin&7 = XCD; 4 bh per XCD -> K/V L2-resident
  const int lin = blockIdx.x;
  const int xcd = lin & 7;
  const int m = lin >> 3;            // 0..127
  const int bh = xcd * 4 + (m & 3);
  const int qb = m >> 2;             // 0..31
  const int b = bh >> 3, hd = bh & 7;

  const bf16* Qb = Q + (size_t)bh * 131072;
  const bf16* Kb = Kk + (size_t)bh * 131072;
  const bf16* Vb = Vt + (size_t)bh * 131072;

  const int q0 = qb * 64 + qg * 32;

  // Q B-frags: col q = q32, k = d = ks*16 + h*8 + j
  bf16x8 qf[4];
#pragma unroll
  for (int ks = 0; ks < 4; ks++)
    qf[ks] = *reinterpret_cast<const bf16x8*>(
        Qb + (size_t)(q0 + q32) * 64 + ks * 16 + h * 8);

  // staging: chunk = 8 rows x 64 = 1KB; wave w stages chunks {2w,2w+1} of K and V
  const int crow = l >> 3;
  const int scol = ((l & 7) ^ crow) * 8;
  auto stage = [&](int kv0, int bb) {
#pragma unroll
    for (int i = 0; i < 2; i++) {
      const int ch = w * 2 + i;
      const int row = ch * 8 + crow;
      gload_lds16(Kb + (size_t)(kv0 + row) * 64 + scol, &Kb2[bb][ch * 512]);
      gload_lds16(Vb + (size_t)row * 2048 + kv0 + scol, &Vb2[bb][ch * 512]);
    }
  };

  f32x16 oacc[2] = {};
  float lsum = 0.f;
  const int l7 = l & 7;

  stage(0, 0);
  asm volatile("s_waitcnt vmcnt(0)" ::: "memory");
  SBAR();

  for (int t = 0; t < 32; t++) {
    const int cur = t & 1;
    if (t < 31) stage((t + 1) * 64, cur ^ 1);

    // K A-frags for this kv-half: row kv = kvh*32 + q32, k = d = ks*16 + h*8 + j
    bf16x8 kb[4];
#pragma unroll
    for (int ks = 0; ks < 4; ks++)
      kb[ks] = *reinterpret_cast<const bf16x8*>(
          &Kb2[cur][(kvh * 32 + q32) * 64 + (((ks * 2 + h) ^ l7) * 8)]);

    // S^T: col = q32, row kv_local = (r&3)+8*(r>>2)+4h  (within the half)
    f32x16 st = {};
#pragma unroll
    for (int ks = 0; ks < 4; ks++)
      st = MFMA32x32x16(kb[ks], qf[ks], st);

    float e[16];
#pragma unroll
    for (int r = 0; r < 16; r++) {
      e[r] = fexp2(st[r]);
      lsum += e[r];
    }
    uint32_t Qp[8];
#pragma unroll
    for (int p = 0; p < 8; p++) Qp[p] = cvtpk(e[2 * p], e[2 * p + 1]);
    plswap(Qp[0], Qp[2]);
    plswap(Qp[1], Qp[3]);
    plswap(Qp[4], Qp[6]);
    plswap(Qp[5], Qp[7]);
    const bf16x8 pa0 = __builtin_bit_cast(bf16x8, (u32x4){Qp[0], Qp[1], Qp[2], Qp[3]});
    const bf16x8 pa1 = __builtin_bit_cast(bf16x8, (u32x4){Qp[4], Qp[5], Qp[6], Qp[7]});

    // PV partial: B = V^T rows d = db*32+q32, k = kv = kvh*32 + kst*16 + h*8 + j
#pragma unroll
    for (int kst = 0; kst < 2; kst++) {
      const bf16x8 pa = (kst == 0) ? pa0 : pa1;
#pragma unroll
      for (int db = 0; db < 2; db++) {
        bf16x8 vb = *reinterpret_cast<const bf16x8*>(
            &Vb2[cur][(db * 32 + q32) * 64 + (((kvh * 4 + kst * 2 + h) ^ l7) * 8)]);
        oacc[db] = MFMA32x32x16(pa, vb, oacc[db]);
      }
    }

    if (t < 31) {
      asm volatile("s_waitcnt vmcnt(0) lgkmcnt(0)" ::: "memory");
      SBAR();
    }
  }

  // lanes l and l+32 hold partials of the same q (within this wave's kv-half)
  lsum += __shfl_xor(lsum, 32);

  // combine kv-halves via dead K/V LDS
  float* cb = (float*)&Kb2[0][0];  // [qg][db][r][lane] = 2*2*16*64 f32 = 16KB
  float* ls = (float*)&Vb2[0][0];  // [qg][32]
  __syncthreads();
  if (kvh == 1) {
#pragma unroll
    for (int db = 0; db < 2; db++)
#pragma unroll
      for (int r = 0; r < 16; r++)
        cb[((qg * 2 + db) * 16 + r) * 64 + l] = oacc[db][r];
    if (l < 32) ls[qg * 32 + q32] = lsum;
  }
  __syncthreads();
  if (kvh == 0) {
    lsum += ls[qg * 32 + q32];
#pragma unroll
    for (int db = 0; db < 2; db++)
#pragma unroll
      for (int r = 0; r < 16; r++)
        oacc[db][r] += cb[((qg * 2 + db) * 16 + r) * 64 + l];

    float inv[16];
#pragma unroll
    for (int r = 0; r < 16; r++) {
      const int qv = (r & 3) + 8 * (r >> 2) + 4 * h;
      inv[r] = 1.f / __shfl(lsum, qv);
    }
#pragma unroll
    for (int db = 0; db < 2; db++) {
#pragma unroll
      for (int r = 0; r < 16; r++) {
        const int qv = (r & 3) + 8 * (r >> 2) + 4 * h;
        AO[(size_t)(b * 2048 + q0 + qv) * 512 + hd * 64 + db * 32 + q32] =
            (bf16)(oacc[db][r] * inv[r]);
      }
    }
  }
}

// ---------------- launch ----------------
extern "C" void kernel_launch(void* const* d_in, const int* in_sizes, int n_in,
                              void* d_out, int out_size, void* d_ws, size_t ws_size,
                              hipStream_t stream) {
  (void)in_sizes; (void)n_in; (void)out_size; (void)ws_size;
  const float* x1 = (const float*)d_in[0];
  const float* x2 = (const float*)d_in[1];
  const float* Wq = (const float*)d_in[2];
  const float* Wk = (const float*)d_in[3];
  const float* Wv = (const float*)d_in[4];
  const float* Wo = (const float*)d_in[5];
  const float* bo = (const float*)d_in[6];

  uint8_t* ws = (uint8_t*)d_ws;
  bf16* x1b = (bf16*)(ws + 0);          // 8,388,608 B
  bf16* x2b = (bf16*)(ws + 8388608);
  bf16* Wsb = (bf16*)(ws + 16777216);   // Wq|Wk|Wv|Wo bf16, 262144 elems each
  bf16* AO  = (bf16*)(ws + 0);          // aliases x1b/x2b (dead after qkv)
  bf16* Qws = (bf16*)(ws + 18874368);   // [b][h][s][64]
  bf16* Kws = (bf16*)(ws + 27262976);   // [b][h][s][64]
  bf16* Vtw = (bf16*)(ws + 35651584);   // [b][h][64][s]

  cast_x<<<4608, 256, 0, stream>>>(x1, x2, Wq, Wk, Wv, Wo, x1b);

  qkv128_kernel<<<dim3(64, 12), 256, 0, stream>>>(x1b, x2b, Wsb, Qws, Kws, Vtw);

  attn_kernel<<<1024, 256, 0, stream>>>(Qws, Kws, Vtw, AO);

  outproj_kernel<<<dim3(64, 8), 256, 0, stream>>>(AO, Wo, (float*)d_out, bo);
}

// Round 13
// 98.259 us; speedup vs baseline: 1.0529x; 1.0529x over previous
//
#include <hip/hip_runtime.h>
#include <stdint.h>

typedef __bf16 bf16;
typedef __bf16 bf16x8 __attribute__((ext_vector_type(8)));
typedef __bf16 bf16x4 __attribute__((ext_vector_type(4)));
typedef float f32x4 __attribute__((ext_vector_type(4)));
typedef float f32x16 __attribute__((ext_vector_type(16)));
typedef uint32_t u32x4 __attribute__((ext_vector_type(4)));

#define MFMA16x16x32(A, B, C) __builtin_amdgcn_mfma_f32_16x16x32_bf16((A), (B), (C), 0, 0, 0)
#define MFMA32x32x16(A, B, C) __builtin_amdgcn_mfma_f32_32x32x16_bf16((A), (B), (C), 0, 0, 0)
#define SBAR() do { __builtin_amdgcn_s_barrier(); __builtin_amdgcn_sched_barrier(0); } while (0)

__device__ __forceinline__ void gload_lds16(const void* g, void* l) {
  __builtin_amdgcn_global_load_lds((const __attribute__((address_space(1))) void*)g,
                                   (__attribute__((address_space(3))) void*)l,
                                   16, 0, 0);
}

__device__ __forceinline__ float fexp2(float x) { return __builtin_amdgcn_exp2f(x); }

__device__ __forceinline__ uint32_t cvtpk(float a, float b) {
  uint32_t r;
  asm("v_cvt_pk_bf16_f32 %0, %1, %2" : "=v"(r) : "v"(a), "v"(b));
  return r;
}
__device__ __forceinline__ void plswap(uint32_t& a, uint32_t& b) {
  asm volatile("v_permlane32_swap_b32 %0, %1" : "+v"(a), "+v"(b));
}

__device__ __forceinline__ bf16x8 cvt8(float4 a, float4 b) {
  bf16x8 o;
  o[0] = (bf16)a.x; o[1] = (bf16)a.y; o[2] = (bf16)a.z; o[3] = (bf16)a.w;
  o[4] = (bf16)b.x; o[5] = (bf16)b.y; o[6] = (bf16)b.z; o[7] = (bf16)b.w;
  return o;
}

// ---------------- inputs + weights -> bf16 (contiguous dst) ----------------
__global__ void cast_x(const float* __restrict__ x1, const float* __restrict__ x2,
                       const float* __restrict__ Wq, const float* __restrict__ Wk,
                       const float* __restrict__ Wv, const float* __restrict__ Wo,
                       bf16* __restrict__ out) {
  const size_t i = ((size_t)blockIdx.x * blockDim.x + threadIdx.x) * 8;
  const float* src;
  if      (i < 4194304u) src = x1 + i;
  else if (i < 8388608u) src = x2 + (i - 4194304u);
  else if (i < 8650752u) src = Wq + (i - 8388608u);
  else if (i < 8912896u) src = Wk + (i - 8650752u);
  else if (i < 9175040u) src = Wv + (i - 8912896u);
  else                   src = Wo + (i - 9175040u);
  float4 a = *reinterpret_cast<const float4*>(src);
  float4 b = *reinterpret_cast<const float4*>(src + 4);
  *reinterpret_cast<bf16x8*>(out + i) = cvt8(a, b);
}

// ---------------- QKV projection (unchanged from r12) ----------------
__global__ __launch_bounds__(256, 3) void qkv128_kernel(
    const bf16* __restrict__ x1b, const bf16* __restrict__ x2b,
    const bf16* __restrict__ Wb, bf16* __restrict__ Qw,
    bf16* __restrict__ Kw, bf16* __restrict__ Vtw) {
  __shared__ bf16 As[3][128 * 32];
  __shared__ bf16 Bs[3][128 * 32];
  const int tid = threadIdx.x;
  const int w = tid >> 6, l = tid & 63;
  const int wr = w >> 1, wc = w & 1;
  const int lr = l & 15, lg = l >> 4;
  const int bm = blockIdx.x, bn = blockIdx.y;
  const int K = 512;
  const int sel = bn >> 2, wn = bn & 3;

  const bf16* A = (sel == 0) ? x1b : x2b;
  const bf16* B = Wb + (size_t)sel * 262144 + (size_t)wn * 128 * K;

  const int c_row = l >> 2;
  const int sw = ((l & 3) ^ (c_row & 3)) * 8;

  auto stage = [&](int t, int bb) {
#pragma unroll
    for (int i = 0; i < 2; i++) {
      const int q = w + i * 4;
      gload_lds16(A + (size_t)(bm * 128 + q * 16 + c_row) * K + t * 32 + sw, &As[bb][q * 512]);
      gload_lds16(B + (size_t)(q * 16 + c_row) * K + t * 32 + sw, &Bs[bb][q * 512]);
    }
  };

  f32x4 acc[4][4] = {};
  const int swz = (lr & 3) * 8;

  stage(0, 0);
  stage(1, 1);
  asm volatile("s_waitcnt vmcnt(4)" ::: "memory");
  SBAR();

  const int NT = 16;
  for (int t = 0; t < NT; t++) {
    if (t + 2 < NT) stage(t + 2, (t + 2) % 3);
    const int cur = t % 3;
    bf16x8 a[4], b[4];
#pragma unroll
    for (int mi = 0; mi < 4; mi++)
      a[mi] = *reinterpret_cast<const bf16x8*>(
          &As[cur][(wr * 64 + mi * 16 + lr) * 32 + (lg * 8 ^ swz)]);
#pragma unroll
    for (int ni = 0; ni < 4; ni++)
      b[ni] = *reinterpret_cast<const bf16x8*>(
          &Bs[cur][(wc * 64 + ni * 16 + lr) * 32 + (lg * 8 ^ swz)]);
#pragma unroll
    for (int mi = 0; mi < 4; mi++)
#pragma unroll
      for (int ni = 0; ni < 4; ni++)
        acc[mi][ni] = MFMA16x16x32(a[mi], b[ni], acc[mi][ni]);

    if (t + 1 < NT) {
      if (t + 2 < NT) asm volatile("s_waitcnt vmcnt(4)" ::: "memory");
      else            asm volatile("s_waitcnt vmcnt(0)" ::: "memory");
      asm volatile("s_waitcnt lgkmcnt(0)" ::: "memory");
      SBAR();
    }
  }

  const float scale = (sel == 0) ? 0.18033688011112f : 1.0f;
#pragma unroll
  for (int mi = 0; mi < 4; mi++) {
    const int m0 = bm * 128 + wr * 64 + mi * 16 + lg * 4;
#pragma unroll
    for (int ni = 0; ni < 4; ni++) {
      const int gn = wn * 128 + wc * 64 + ni * 16 + lr;
      if (sel < 2) {
        bf16* dst = (sel == 0) ? Qw : Kw;
#pragma unroll
        for (int r = 0; r < 4; r++) {
          const int m = m0 + r;
          size_t d = (size_t)((m >> 11) * 8 + (gn >> 6)) * 131072 + (size_t)(m & 2047) * 64 + (gn & 63);
          dst[d] = (bf16)(acc[mi][ni][r] * scale);
        }
      } else {
        bf16x4 pv;
#pragma unroll
        for (int r = 0; r < 4; r++) pv[r] = (bf16)acc[mi][ni][r];
        size_t base = ((size_t)(m0 >> 11) * 512 + gn) * 2048 + (m0 & 2047);
        *reinterpret_cast<bf16x4*>(Vtw + base) = pv;
      }
    }
  }
}

// ---------------- out projection (unchanged from r12) ----------------
__global__ __launch_bounds__(256, 4) void outproj_kernel(
    const bf16* __restrict__ A0, const float* __restrict__ W0,
    float* __restrict__ C0, const float* __restrict__ bias) {
  __shared__ bf16 As[3][128 * 32];
  __shared__ bf16 Bs[2][64 * 32];
  const int tid = threadIdx.x;
  const int w = tid >> 6, l = tid & 63;
  const int wr = w >> 1, wc = w & 1;
  const int lr = l & 15, lg = l >> 4;
  const int bm = blockIdx.x, bn = blockIdx.y;
  const int K = 512;

  const float* Bf = W0 + (size_t)bn * 64 * K;
  const int c_row = l >> 2;
  const int c_s = l & 3;
  const int sw = (c_s ^ (c_row & 3)) * 8;

  float4 lb[2][2];
  auto issue_A = [&](int t, int bb) {
#pragma unroll
    for (int i = 0; i < 2; i++) {
      const int q = w + i * 4;
      gload_lds16(A0 + (size_t)(bm * 128 + q * 16 + c_row) * K + t * 32 + sw, &As[bb][q * 512]);
    }
  };
  auto issue_B = [&](int t, int s) {
    const float* pb = Bf + (size_t)(w * 16 + c_row) * K + t * 32 + c_s * 8;
    lb[s][0] = *reinterpret_cast<const float4*>(pb);
    lb[s][1] = *reinterpret_cast<const float4*>(pb + 4);
  };
  auto commit_B = [&](int s, int bb) {
    *reinterpret_cast<bf16x8*>(&Bs[bb][w * 512 + c_row * 32 + sw]) = cvt8(lb[s][0], lb[s][1]);
  };

  f32x4 acc[4][2] = {};
  const int swz = (lr & 3) * 8;

  issue_A(0, 0); issue_B(0, 0);
  issue_A(1, 1); issue_B(1, 1);
  asm volatile("s_waitcnt vmcnt(4)" ::: "memory");
  commit_B(0, 0);
  asm volatile("s_waitcnt lgkmcnt(0)" ::: "memory");
  SBAR();

  const int NT = 16;
  for (int t = 0; t < NT; t++) {
    if (t + 2 < NT) { issue_A(t + 2, (t + 2) % 3); issue_B(t + 2, t & 1); }

    bf16x8 a[4], b[2];
    const int cur = t % 3;
#pragma unroll
    for (int mi = 0; mi < 4; mi++)
      a[mi] = *reinterpret_cast<const bf16x8*>(
          &As[cur][(wr * 64 + mi * 16 + lr) * 32 + (lg * 8 ^ swz)]);
#pragma unroll
    for (int ni = 0; ni < 2; ni++)
      b[ni] = *reinterpret_cast<const bf16x8*>(
          &Bs[t & 1][(wc * 32 + ni * 16 + lr) * 32 + (lg * 8 ^ swz)]);
#pragma unroll
    for (int mi = 0; mi < 4; mi++)
#pragma unroll
      for (int ni = 0; ni < 2; ni++)
        acc[mi][ni] = MFMA16x16x32(a[mi], b[ni], acc[mi][ni]);

    if (t + 1 < NT) {
      if (t + 2 < NT) asm volatile("s_waitcnt vmcnt(4)" ::: "memory");
      else            asm volatile("s_waitcnt vmcnt(0)" ::: "memory");
      commit_B((t + 1) & 1, (t + 1) & 1);
      asm volatile("s_waitcnt lgkmcnt(0)" ::: "memory");
      SBAR();
    }
  }

#pragma unroll
  for (int mi = 0; mi < 4; mi++) {
    const int m0 = bm * 128 + wr * 64 + mi * 16 + lg * 4;
#pragma unroll
    for (int ni = 0; ni < 2; ni++) {
      const int gn = bn * 64 + wc * 32 + ni * 16 + lr;
      const float bv = bias[gn];
#pragma unroll
      for (int r = 0; r < 4; r++)
        C0[(size_t)(m0 + r) * 512 + gn] = acc[mi][ni][r] + bv;
    }
  }
}

// ---------------- flash attention: 32x32 in-reg P, kv-split, 8-wave blocks -----------
// Block: 512 thr = 8 waves = 4 q-groups x 2 kv-halves; 128 q/block; grid 512.
// 2 blocks/CU -> 16 waves/CU (4/SIMD) with only 2 K/V staging streams per CU
// (r12 had 4 streams at the same occupancy -> staging-bound). Ring-2 LDS 32KB.
// Per wave-iter: 2 glds, 8 ds_read_b128, 8 MFMA, 16 exp2. O combined once via dead LDS.
__global__ __launch_bounds__(512, 2) void attn_kernel(
    const bf16* __restrict__ Q, const bf16* __restrict__ Kk,
    const bf16* __restrict__ Vt, bf16* __restrict__ AO) {
  __shared__ bf16 KV[2][2][64 * 64];  // [K|V][ring][tile] = 32KB contiguous
  __shared__ float ls[4][32];         // 512B lsum combine

  const int tid = threadIdx.x;
  const int w = tid >> 6, l = tid & 63;  // w 0..7
  const int q32 = l & 31;
  const int h = l >> 5;
  const int qg = w >> 1, kvh = w & 1;

  // XCD-aware decode: grid 512, lin&7 = XCD; 4 bh per XCD -> K/V L2-resident
  const int lin = blockIdx.x;
  const int xcd = lin & 7;
  const int m = lin >> 3;            // 0..63
  const int bh = xcd * 4 + (m & 3);
  const int qb = m >> 2;             // 0..15
  const int b = bh >> 3, hd = bh & 7;

  const bf16* Qb = Q + (size_t)bh * 131072;
  const bf16* Kb = Kk + (size_t)bh * 131072;
  const bf16* Vb = Vt + (size_t)bh * 131072;

  const int q0 = qb * 128 + qg * 32;

  // Q B-frags: col q = q32, k = d = ks*16 + h*8 + j
  bf16x8 qf[4];
#pragma unroll
  for (int ks = 0; ks < 4; ks++)
    qf[ks] = *reinterpret_cast<const bf16x8*>(
        Qb + (size_t)(q0 + q32) * 64 + ks * 16 + h * 8);

  // staging: 16 chunks of 8 rows x 64 (K: 8 chunks, V: 8 chunks); wave w stages
  // K-chunk w and V-chunk w -> 2 glds per wave per tile.
  const int crow = l >> 3;
  const int scol = ((l & 7) ^ crow) * 8;
  auto stage = [&](int kv0, int bb) {
    const int row = w * 8 + crow;
    gload_lds16(Kb + (size_t)(kv0 + row) * 64 + scol, &KV[0][bb][w * 512]);
    gload_lds16(Vb + (size_t)row * 2048 + kv0 + scol, &KV[1][bb][w * 512]);
  };

  f32x16 oacc[2] = {};
  float lsum = 0.f;
  const int l7 = l & 7;

  stage(0, 0);
  asm volatile("s_waitcnt vmcnt(0)" ::: "memory");
  SBAR();

  for (int t = 0; t < 32; t++) {
    const int cur = t & 1;
    if (t < 31) stage((t + 1) * 64, cur ^ 1);

    // K A-frags for this kv-half: row kv = kvh*32 + q32 (row&7 == l&7)
    bf16x8 kb[4];
#pragma unroll
    for (int ks = 0; ks < 4; ks++)
      kb[ks] = *reinterpret_cast<const bf16x8*>(
          &KV[0][cur][(kvh * 32 + q32) * 64 + (((ks * 2 + h) ^ l7) * 8)]);

    // S^T: col = q32, row kv_local = (r&3)+8*(r>>2)+4h (within the half)
    f32x16 st = {};
#pragma unroll
    for (int ks = 0; ks < 4; ks++)
      st = MFMA32x32x16(kb[ks], qf[ks], st);

    float e[16];
#pragma unroll
    for (int r = 0; r < 16; r++) {
      e[r] = fexp2(st[r]);
      lsum += e[r];
    }
    uint32_t Qp[8];
#pragma unroll
    for (int p = 0; p < 8; p++) Qp[p] = cvtpk(e[2 * p], e[2 * p + 1]);
    plswap(Qp[0], Qp[2]);
    plswap(Qp[1], Qp[3]);
    plswap(Qp[4], Qp[6]);
    plswap(Qp[5], Qp[7]);
    const bf16x8 pa0 = __builtin_bit_cast(bf16x8, (u32x4){Qp[0], Qp[1], Qp[2], Qp[3]});
    const bf16x8 pa1 = __builtin_bit_cast(bf16x8, (u32x4){Qp[4], Qp[5], Qp[6], Qp[7]});

    // PV partial: B = V^T rows d = db*32+q32, k = kv = kvh*32 + kst*16 + h*8 + j
#pragma unroll
    for (int kst = 0; kst < 2; kst++) {
      const bf16x8 pa = (kst == 0) ? pa0 : pa1;
#pragma unroll
      for (int db = 0; db < 2; db++) {
        bf16x8 vb = *reinterpret_cast<const bf16x8*>(
            &KV[1][cur][(db * 32 + q32) * 64 + (((kvh * 4 + kst * 2 + h) ^ l7) * 8)]);
        oacc[db] = MFMA32x32x16(pa, vb, oacc[db]);
      }
    }

    if (t < 31) {
      asm volatile("s_waitcnt vmcnt(0) lgkmcnt(0)" ::: "memory");
      SBAR();
    }
  }

  // lanes l and l+32 hold partials of the same q (within this wave's kv-half)
  lsum += __shfl_xor(lsum, 32);

  // combine kv-halves via dead K/V LDS (32KB contiguous f32 buffer)
  float* cb = (float*)&KV[0][0][0];  // [qg][db][r][lane] = 4*2*16*64 f32 = 32KB
  __syncthreads();
  if (kvh == 1) {
#pragma unroll
    for (int db = 0; db < 2; db++)
#pragma unroll
      for (int r = 0; r < 16; r++)
        cb[((qg * 4 + db * 2 + (r >> 3)) * 8 + (r & 7)) * 64 + l] = oacc[db][r];
    if (l < 32) ls[qg][q32] = lsum;
  }
  __syncthreads();
  if (kvh == 0) {
    lsum += ls[qg][q32];
#pragma unroll
    for (int db = 0; db < 2; db++)
#pragma unroll
      for (int r = 0; r < 16; r++)
        oacc[db][r] += cb[((qg * 4 + db * 2 + (r >> 3)) * 8 + (r & 7)) * 64 + l];

    float inv[16];
#pragma unroll
    for (int r = 0; r < 16; r++) {
      const int qv = (r & 3) + 8 * (r >> 2) + 4 * h;
      inv[r] = 1.f / __shfl(lsum, qv);
    }
#pragma unroll
    for (int db = 0; db < 2; db++) {
#pragma unroll
      for (int r = 0; r < 16; r++) {
        const int qv = (r & 3) + 8 * (r >> 2) + 4 * h;
        AO[(size_t)(b * 2048 + q0 + qv) * 512 + hd * 64 + db * 32 + q32] =
            (bf16)(oacc[db][r] * inv[r]);
      }
    }
  }
}

// ---------------- launch ----------------
extern "C" void kernel_launch(void* const* d_in, const int* in_sizes, int n_in,
                              void* d_out, int out_size, void* d_ws, size_t ws_size,
                              hipStream_t stream) {
  (void)in_sizes; (void)n_in; (void)out_size; (void)ws_size;
  const float* x1 = (const float*)d_in[0];
  const float* x2 = (const float*)d_in[1];
  const float* Wq = (const float*)d_in[2];
  const float* Wk = (const float*)d_in[3];
  const float* Wv = (const float*)d_in[4];
  const float* Wo = (const float*)d_in[5];
  const float* bo = (const float*)d_in[6];

  uint8_t* ws = (uint8_t*)d_ws;
  bf16* x1b = (bf16*)(ws + 0);
  bf16* x2b = (bf16*)(ws + 8388608);
  bf16* Wsb = (bf16*)(ws + 16777216);   // Wq|Wk|Wv|Wo bf16
  bf16* AO  = (bf16*)(ws + 0);          // aliases x1b/x2b (dead after qkv)
  bf16* Qws = (bf16*)(ws + 18874368);
  bf16* Kws = (bf16*)(ws + 27262976);
  bf16* Vtw = (bf16*)(ws + 35651584);

  cast_x<<<4608, 256, 0, stream>>>(x1, x2, Wq, Wk, Wv, Wo, x1b);

  qkv128_kernel<<<dim3(64, 12), 256, 0, stream>>>(x1b, x2b, Wsb, Qws, Kws, Vtw);

  attn_kernel<<<512, 512, 0, stream>>>(Qws, Kws, Vtw, AO);

  outproj_kernel<<<dim3(64, 8), 256, 0, stream>>>(AO, Wo, (float*)d_out, bo);
}

// Round 14
// 97.013 us; speedup vs baseline: 1.0664x; 1.0128x over previous
//
#include <hip/hip_runtime.h>
#include <stdint.h>

typedef __bf16 bf16;
typedef __bf16 bf16x8 __attribute__((ext_vector_type(8)));
typedef __bf16 bf16x4 __attribute__((ext_vector_type(4)));
typedef float f32x4 __attribute__((ext_vector_type(4)));
typedef float f32x16 __attribute__((ext_vector_type(16)));
typedef uint32_t u32x4 __attribute__((ext_vector_type(4)));

#define MFMA16x16x32(A, B, C) __builtin_amdgcn_mfma_f32_16x16x32_bf16((A), (B), (C), 0, 0, 0)
#define MFMA32x32x16(A, B, C) __builtin_amdgcn_mfma_f32_32x32x16_bf16((A), (B), (C), 0, 0, 0)
#define SBAR() do { __builtin_amdgcn_s_barrier(); __builtin_amdgcn_sched_barrier(0); } while (0)

__device__ __forceinline__ void gload_lds16(const void* g, void* l) {
  __builtin_amdgcn_global_load_lds((const __attribute__((address_space(1))) void*)g,
                                   (__attribute__((address_space(3))) void*)l,
                                   16, 0, 0);
}

__device__ __forceinline__ float fexp2(float x) { return __builtin_amdgcn_exp2f(x); }

__device__ __forceinline__ uint32_t cvtpk(float a, float b) {
  uint32_t r;
  asm("v_cvt_pk_bf16_f32 %0, %1, %2" : "=v"(r) : "v"(a), "v"(b));
  return r;
}
__device__ __forceinline__ void plswap(uint32_t& a, uint32_t& b) {
  asm volatile("v_permlane32_swap_b32 %0, %1" : "+v"(a), "+v"(b));
}

__device__ __forceinline__ bf16x8 cvt8(float4 a, float4 b) {
  bf16x8 o;
  o[0] = (bf16)a.x; o[1] = (bf16)a.y; o[2] = (bf16)a.z; o[3] = (bf16)a.w;
  o[4] = (bf16)b.x; o[5] = (bf16)b.y; o[6] = (bf16)b.z; o[7] = (bf16)b.w;
  return o;
}

// ---------------- inputs + weights -> bf16 (contiguous dst) ----------------
__global__ void cast_x(const float* __restrict__ x1, const float* __restrict__ x2,
                       const float* __restrict__ Wq, const float* __restrict__ Wk,
                       const float* __restrict__ Wv, const float* __restrict__ Wo,
                       bf16* __restrict__ out) {
  const size_t i = ((size_t)blockIdx.x * blockDim.x + threadIdx.x) * 8;
  const float* src;
  if      (i < 4194304u) src = x1 + i;
  else if (i < 8388608u) src = x2 + (i - 4194304u);
  else if (i < 8650752u) src = Wq + (i - 8388608u);
  else if (i < 8912896u) src = Wk + (i - 8650752u);
  else if (i < 9175040u) src = Wv + (i - 8912896u);
  else                   src = Wo + (i - 9175040u);
  float4 a = *reinterpret_cast<const float4*>(src);
  float4 b = *reinterpret_cast<const float4*>(src + 4);
  *reinterpret_cast<bf16x8*>(out + i) = cvt8(a, b);
}

// ---------------- QKV projection (unchanged from r13) ----------------
__global__ __launch_bounds__(256, 3) void qkv128_kernel(
    const bf16* __restrict__ x1b, const bf16* __restrict__ x2b,
    const bf16* __restrict__ Wb, bf16* __restrict__ Qw,
    bf16* __restrict__ Kw, bf16* __restrict__ Vtw) {
  __shared__ bf16 As[3][128 * 32];
  __shared__ bf16 Bs[3][128 * 32];
  const int tid = threadIdx.x;
  const int w = tid >> 6, l = tid & 63;
  const int wr = w >> 1, wc = w & 1;
  const int lr = l & 15, lg = l >> 4;
  const int bm = blockIdx.x, bn = blockIdx.y;
  const int K = 512;
  const int sel = bn >> 2, wn = bn & 3;

  const bf16* A = (sel == 0) ? x1b : x2b;
  const bf16* B = Wb + (size_t)sel * 262144 + (size_t)wn * 128 * K;

  const int c_row = l >> 2;
  const int sw = ((l & 3) ^ (c_row & 3)) * 8;

  auto stage = [&](int t, int bb) {
#pragma unroll
    for (int i = 0; i < 2; i++) {
      const int q = w + i * 4;
      gload_lds16(A + (size_t)(bm * 128 + q * 16 + c_row) * K + t * 32 + sw, &As[bb][q * 512]);
      gload_lds16(B + (size_t)(q * 16 + c_row) * K + t * 32 + sw, &Bs[bb][q * 512]);
    }
  };

  f32x4 acc[4][4] = {};
  const int swz = (lr & 3) * 8;

  stage(0, 0);
  stage(1, 1);
  asm volatile("s_waitcnt vmcnt(4)" ::: "memory");
  SBAR();

  const int NT = 16;
  for (int t = 0; t < NT; t++) {
    if (t + 2 < NT) stage(t + 2, (t + 2) % 3);
    const int cur = t % 3;
    bf16x8 a[4], b[4];
#pragma unroll
    for (int mi = 0; mi < 4; mi++)
      a[mi] = *reinterpret_cast<const bf16x8*>(
          &As[cur][(wr * 64 + mi * 16 + lr) * 32 + (lg * 8 ^ swz)]);
#pragma unroll
    for (int ni = 0; ni < 4; ni++)
      b[ni] = *reinterpret_cast<const bf16x8*>(
          &Bs[cur][(wc * 64 + ni * 16 + lr) * 32 + (lg * 8 ^ swz)]);
#pragma unroll
    for (int mi = 0; mi < 4; mi++)
#pragma unroll
      for (int ni = 0; ni < 4; ni++)
        acc[mi][ni] = MFMA16x16x32(a[mi], b[ni], acc[mi][ni]);

    if (t + 1 < NT) {
      if (t + 2 < NT) asm volatile("s_waitcnt vmcnt(4)" ::: "memory");
      else            asm volatile("s_waitcnt vmcnt(0)" ::: "memory");
      asm volatile("s_waitcnt lgkmcnt(0)" ::: "memory");
      SBAR();
    }
  }

  const float scale = (sel == 0) ? 0.18033688011112f : 1.0f;
#pragma unroll
  for (int mi = 0; mi < 4; mi++) {
    const int m0 = bm * 128 + wr * 64 + mi * 16 + lg * 4;
#pragma unroll
    for (int ni = 0; ni < 4; ni++) {
      const int gn = wn * 128 + wc * 64 + ni * 16 + lr;
      if (sel < 2) {
        bf16* dst = (sel == 0) ? Qw : Kw;
#pragma unroll
        for (int r = 0; r < 4; r++) {
          const int m = m0 + r;
          size_t d = (size_t)((m >> 11) * 8 + (gn >> 6)) * 131072 + (size_t)(m & 2047) * 64 + (gn & 63);
          dst[d] = (bf16)(acc[mi][ni][r] * scale);
        }
      } else {
        bf16x4 pv;
#pragma unroll
        for (int r = 0; r < 4; r++) pv[r] = (bf16)acc[mi][ni][r];
        size_t base = ((size_t)(m0 >> 11) * 512 + gn) * 2048 + (m0 & 2047);
        *reinterpret_cast<bf16x4*>(Vtw + base) = pv;
      }
    }
  }
}

// ---------------- out projection (unchanged from r13) ----------------
__global__ __launch_bounds__(256, 4) void outproj_kernel(
    const bf16* __restrict__ A0, const float* __restrict__ W0,
    float* __restrict__ C0, const float* __restrict__ bias) {
  __shared__ bf16 As[3][128 * 32];
  __shared__ bf16 Bs[2][64 * 32];
  const int tid = threadIdx.x;
  const int w = tid >> 6, l = tid & 63;
  const int wr = w >> 1, wc = w & 1;
  const int lr = l & 15, lg = l >> 4;
  const int bm = blockIdx.x, bn = blockIdx.y;
  const int K = 512;

  const float* Bf = W0 + (size_t)bn * 64 * K;
  const int c_row = l >> 2;
  const int c_s = l & 3;
  const int sw = (c_s ^ (c_row & 3)) * 8;

  float4 lb[2][2];
  auto issue_A = [&](int t, int bb) {
#pragma unroll
    for (int i = 0; i < 2; i++) {
      const int q = w + i * 4;
      gload_lds16(A0 + (size_t)(bm * 128 + q * 16 + c_row) * K + t * 32 + sw, &As[bb][q * 512]);
    }
  };
  auto issue_B = [&](int t, int s) {
    const float* pb = Bf + (size_t)(w * 16 + c_row) * K + t * 32 + c_s * 8;
    lb[s][0] = *reinterpret_cast<const float4*>(pb);
    lb[s][1] = *reinterpret_cast<const float4*>(pb + 4);
  };
  auto commit_B = [&](int s, int bb) {
    *reinterpret_cast<bf16x8*>(&Bs[bb][w * 512 + c_row * 32 + sw]) = cvt8(lb[s][0], lb[s][1]);
  };

  f32x4 acc[4][2] = {};
  const int swz = (lr & 3) * 8;

  issue_A(0, 0); issue_B(0, 0);
  issue_A(1, 1); issue_B(1, 1);
  asm volatile("s_waitcnt vmcnt(4)" ::: "memory");
  commit_B(0, 0);
  asm volatile("s_waitcnt lgkmcnt(0)" ::: "memory");
  SBAR();

  const int NT = 16;
  for (int t = 0; t < NT; t++) {
    if (t + 2 < NT) { issue_A(t + 2, (t + 2) % 3); issue_B(t + 2, t & 1); }

    bf16x8 a[4], b[2];
    const int cur = t % 3;
#pragma unroll
    for (int mi = 0; mi < 4; mi++)
      a[mi] = *reinterpret_cast<const bf16x8*>(
          &As[cur][(wr * 64 + mi * 16 + lr) * 32 + (lg * 8 ^ swz)]);
#pragma unroll
    for (int ni = 0; ni < 2; ni++)
      b[ni] = *reinterpret_cast<const bf16x8*>(
          &Bs[t & 1][(wc * 32 + ni * 16 + lr) * 32 + (lg * 8 ^ swz)]);
#pragma unroll
    for (int mi = 0; mi < 4; mi++)
#pragma unroll
      for (int ni = 0; ni < 2; ni++)
        acc[mi][ni] = MFMA16x16x32(a[mi], b[ni], acc[mi][ni]);

    if (t + 1 < NT) {
      if (t + 2 < NT) asm volatile("s_waitcnt vmcnt(4)" ::: "memory");
      else            asm volatile("s_waitcnt vmcnt(0)" ::: "memory");
      commit_B((t + 1) & 1, (t + 1) & 1);
      asm volatile("s_waitcnt lgkmcnt(0)" ::: "memory");
      SBAR();
    }
  }

#pragma unroll
  for (int mi = 0; mi < 4; mi++) {
    const int m0 = bm * 128 + wr * 64 + mi * 16 + lg * 4;
#pragma unroll
    for (int ni = 0; ni < 2; ni++) {
      const int gn = bn * 64 + wc * 32 + ni * 16 + lr;
      const float bv = bias[gn];
#pragma unroll
      for (int r = 0; r < 4; r++)
        C0[(size_t)(m0 + r) * 512 + gn] = acc[mi][ni][r] + bv;
    }
  }
}

// ---------------- flash attention: 64 q/wave, reads/MFMA = 0.5 ----------------
// Block: 512 thr = 8 waves = 4 q-groups(64 q) x 2 kv-halves; 256 q/block; grid 256
// (1 block/CU -> single K/V staging stream). Each kb/vb frag read feeds TWO MFMAs
// (q-sub-blocks i=0,1 share K and V) -> per wave-iter: 8 b128 reads, 16 MFMA,
// 32 exp2. Two independent QK chains per wave supply ILP at 2 waves/SIMD.
__global__ __launch_bounds__(512, 1) void attn_kernel(
    const bf16* __restrict__ Q, const bf16* __restrict__ Kk,
    const bf16* __restrict__ Vt, bf16* __restrict__ AO) {
  __shared__ bf16 KV[2][2][64 * 64];  // [K|V][ring][tile] = 32KB
  __shared__ float cls[4][2][32];     // lsum combine

  const int tid = threadIdx.x;
  const int w = tid >> 6, l = tid & 63;  // w 0..7
  const int q32 = l & 31;
  const int h = l >> 5;
  const int qg = w >> 1, kvh = w & 1;

  // XCD-aware decode: grid 256, lin&7 = XCD; 4 bh per XCD -> K/V L2-resident
  const int lin = blockIdx.x;
  const int xcd = lin & 7;
  const int m = lin >> 3;            // 0..31
  const int bh = xcd * 4 + (m & 3);
  const int qb = m >> 2;             // 0..7
  const int b = bh >> 3, hd = bh & 7;

  const bf16* Qb = Q + (size_t)bh * 131072;
  const bf16* Kb = Kk + (size_t)bh * 131072;
  const bf16* Vb = Vt + (size_t)bh * 131072;

  const int q0 = qb * 256 + qg * 64;

  // Q B-frags: sub-block i, col q = q32, k = d = ks*16 + h*8 + j
  bf16x8 qf[2][4];
#pragma unroll
  for (int i = 0; i < 2; i++)
#pragma unroll
    for (int ks = 0; ks < 4; ks++)
      qf[i][ks] = *reinterpret_cast<const bf16x8*>(
          Qb + (size_t)(q0 + i * 32 + q32) * 64 + ks * 16 + h * 8);

  // staging: wave w stages K-chunk w and V-chunk w (8 rows x 64 each, 1KB)
  const int crow = l >> 3;
  const int scol = ((l & 7) ^ crow) * 8;
  auto stage = [&](int kv0, int bb) {
    const int row = w * 8 + crow;
    gload_lds16(Kb + (size_t)(kv0 + row) * 64 + scol, &KV[0][bb][w * 512]);
    gload_lds16(Vb + (size_t)row * 2048 + kv0 + scol, &KV[1][bb][w * 512]);
  };

  f32x16 oacc[2][2] = {};  // [i][db]
  float lsum[2] = {0.f, 0.f};
  const int l7 = l & 7;

  stage(0, 0);
  asm volatile("s_waitcnt vmcnt(0)" ::: "memory");
  SBAR();

  for (int t = 0; t < 32; t++) {
    const int cur = t & 1;
    if (t < 31) stage((t + 1) * 64, cur ^ 1);

    // K A-frags for this kv-half: row kv = kvh*32 + q32 (shared by both q-sub-blocks)
    bf16x8 kb[4];
#pragma unroll
    for (int ks = 0; ks < 4; ks++)
      kb[ks] = *reinterpret_cast<const bf16x8*>(
          &KV[0][cur][(kvh * 32 + q32) * 64 + (((ks * 2 + h) ^ l7) * 8)]);

    bf16x8 pa[2][2];
#pragma unroll
    for (int i = 0; i < 2; i++) {
      // S^T: col = q32 (of sub-block i), row kv_local = (r&3)+8*(r>>2)+4h
      f32x16 st = {};
#pragma unroll
      for (int ks = 0; ks < 4; ks++)
        st = MFMA32x32x16(kb[ks], qf[i][ks], st);

      float e[16];
#pragma unroll
      for (int r = 0; r < 16; r++) {
        e[r] = fexp2(st[r]);
        lsum[i] += e[r];
      }
      uint32_t Qp[8];
#pragma unroll
      for (int p = 0; p < 8; p++) Qp[p] = cvtpk(e[2 * p], e[2 * p + 1]);
      plswap(Qp[0], Qp[2]);
      plswap(Qp[1], Qp[3]);
      plswap(Qp[4], Qp[6]);
      plswap(Qp[5], Qp[7]);
      pa[i][0] = __builtin_bit_cast(bf16x8, (u32x4){Qp[0], Qp[1], Qp[2], Qp[3]});
      pa[i][1] = __builtin_bit_cast(bf16x8, (u32x4){Qp[4], Qp[5], Qp[6], Qp[7]});
    }

    // V B-frags (shared by both q-sub-blocks): rows d = db*32+q32
    bf16x8 vb[2][2];
#pragma unroll
    for (int kst = 0; kst < 2; kst++)
#pragma unroll
      for (int db = 0; db < 2; db++)
        vb[kst][db] = *reinterpret_cast<const bf16x8*>(
            &KV[1][cur][(db * 32 + q32) * 64 + (((kvh * 4 + kst * 2 + h) ^ l7) * 8)]);

    // PV partials
#pragma unroll
    for (int i = 0; i < 2; i++)
#pragma unroll
      for (int kst = 0; kst < 2; kst++)
#pragma unroll
        for (int db = 0; db < 2; db++)
          oacc[i][db] = MFMA32x32x16(pa[i][kst], vb[kst][db], oacc[i][db]);

    if (t < 31) {
      asm volatile("s_waitcnt vmcnt(0) lgkmcnt(0)" ::: "memory");
      SBAR();
    }
  }

  // lanes l and l+32 hold partials of the same q (within this wave's kv-half)
#pragma unroll
  for (int i = 0; i < 2; i++) lsum[i] += __shfl_xor(lsum[i], 32);

  // combine kv-halves via dead K/V LDS (8192 f32 = 32KB), two passes (i=0, i=1)
  float* cb = (float*)&KV[0][0][0];
  __syncthreads();
  if (kvh == 1 && l < 32) {
    cls[qg][0][q32] = lsum[0];
    cls[qg][1][q32] = lsum[1];
  }
#pragma unroll
  for (int i = 0; i < 2; i++) {
    if (kvh == 1) {
#pragma unroll
      for (int db = 0; db < 2; db++)
#pragma unroll
        for (int r = 0; r < 16; r++)
          cb[((qg * 2 + db) * 16 + r) * 64 + l] = oacc[i][db][r];
    }
    __syncthreads();
    if (kvh == 0) {
#pragma unroll
      for (int db = 0; db < 2; db++)
#pragma unroll
        for (int r = 0; r < 16; r++)
          oacc[i][db][r] += cb[((qg * 2 + db) * 16 + r) * 64 + l];
    }
    __syncthreads();
  }

  if (kvh == 0) {
#pragma unroll
    for (int i = 0; i < 2; i++) {
      lsum[i] += cls[qg][i][q32];
      float inv[16];
#pragma unroll
      for (int r = 0; r < 16; r++) {
        const int qv = (r & 3) + 8 * (r >> 2) + 4 * h;
        inv[r] = 1.f / __shfl(lsum[i], qv);
      }
#pragma unroll
      for (int db = 0; db < 2; db++) {
#pragma unroll
        for (int r = 0; r < 16; r++) {
          const int qv = (r & 3) + 8 * (r >> 2) + 4 * h;
          AO[(size_t)(b * 2048 + q0 + i * 32 + qv) * 512 + hd * 64 + db * 32 + q32] =
              (bf16)(oacc[i][db][r] * inv[r]);
        }
      }
    }
  }
}

// ---------------- launch ----------------
extern "C" void kernel_launch(void* const* d_in, const int* in_sizes, int n_in,
                              void* d_out, int out_size, void* d_ws, size_t ws_size,
                              hipStream_t stream) {
  (void)in_sizes; (void)n_in; (void)out_size; (void)ws_size;
  const float* x1 = (const float*)d_in[0];
  const float* x2 = (const float*)d_in[1];
  const float* Wq = (const float*)d_in[2];
  const float* Wk = (const float*)d_in[3];
  const float* Wv = (const float*)d_in[4];
  const float* Wo = (const float*)d_in[5];
  const float* bo = (const float*)d_in[6];

  uint8_t* ws = (uint8_t*)d_ws;
  bf16* x1b = (bf16*)(ws + 0);
  bf16* x2b = (bf16*)(ws + 8388608);
  bf16* Wsb = (bf16*)(ws + 16777216);   // Wq|Wk|Wv|Wo bf16
  bf16* AO  = (bf16*)(ws + 0);          // aliases x1b/x2b (dead after qkv)
  bf16* Qws = (bf16*)(ws + 18874368);
  bf16* Kws = (bf16*)(ws + 27262976);
  bf16* Vtw = (bf16*)(ws + 35651584);

  cast_x<<<4608, 256, 0, stream>>>(x1, x2, Wq, Wk, Wv, Wo, x1b);

  qkv128_kernel<<<dim3(64, 12), 256, 0, stream>>>(x1b, x2b, Wsb, Qws, Kws, Vtw);

  attn_kernel<<<256, 512, 0, stream>>>(Qws, Kws, Vtw, AO);

  outproj_kernel<<<dim3(64, 8), 256, 0, stream>>>(AO, Wo, (float*)d_out, bo);
}

// Round 15
// 96.737 us; speedup vs baseline: 1.0695x; 1.0029x over previous
//
#include <hip/hip_runtime.h>
#include <stdint.h>

typedef __bf16 bf16;
typedef __bf16 bf16x8 __attribute__((ext_vector_type(8)));
typedef __bf16 bf16x4 __attribute__((ext_vector_type(4)));
typedef float f32x4 __attribute__((ext_vector_type(4)));
typedef float f32x16 __attribute__((ext_vector_type(16)));
typedef uint32_t u32x4 __attribute__((ext_vector_type(4)));

#define MFMA16x16x32(A, B, C) __builtin_amdgcn_mfma_f32_16x16x32_bf16((A), (B), (C), 0, 0, 0)
#define MFMA32x32x16(A, B, C) __builtin_amdgcn_mfma_f32_32x32x16_bf16((A), (B), (C), 0, 0, 0)
#define SBAR() do { __builtin_amdgcn_s_barrier(); __builtin_amdgcn_sched_barrier(0); } while (0)

__device__ __forceinline__ void gload_lds16(const void* g, void* l) {
  __builtin_amdgcn_global_load_lds((const __attribute__((address_space(1))) void*)g,
                                   (__attribute__((address_space(3))) void*)l,
                                   16, 0, 0);
}

__device__ __forceinline__ float fexp2(float x) { return __builtin_amdgcn_exp2f(x); }

__device__ __forceinline__ uint32_t cvtpk(float a, float b) {
  uint32_t r;
  asm("v_cvt_pk_bf16_f32 %0, %1, %2" : "=v"(r) : "v"(a), "v"(b));
  return r;
}
__device__ __forceinline__ void plswap(uint32_t& a, uint32_t& b) {
  asm volatile("v_permlane32_swap_b32 %0, %1" : "+v"(a), "+v"(b));
}

__device__ __forceinline__ bf16x8 cvt8(float4 a, float4 b) {
  bf16x8 o;
  o[0] = (bf16)a.x; o[1] = (bf16)a.y; o[2] = (bf16)a.z; o[3] = (bf16)a.w;
  o[4] = (bf16)b.x; o[5] = (bf16)b.y; o[6] = (bf16)b.z; o[7] = (bf16)b.w;
  return o;
}

// ---------------- QKV projection with FUSED f32->bf16 cast ----------------
// 128x128 tile, BK=32, ring-3 LDS. Both A (x1/x2) and W staged f32 -> reg -> cvt ->
// LDS with 2-iteration-ahead issue and counted vmcnt(8) (never 0 mid-loop) — the
// r6 cast-fusion failure was 1-deep issue with in-iteration drain; this is 2-deep.
// Register sets are compile-time indexed via unroll-2 (rule #20).
// grid (64, 12): bn<4 -> Q (x1, *0.125*log2e), bn<8 -> K (x2), else V^T (x2).
__global__ __launch_bounds__(256, 2) void qkv128_kernel(
    const float* __restrict__ x1, const float* __restrict__ x2,
    const float* __restrict__ Wq, const float* __restrict__ Wk,
    const float* __restrict__ Wv, bf16* __restrict__ Qw,
    bf16* __restrict__ Kw, bf16* __restrict__ Vtw) {
  __shared__ bf16 As[3][128 * 32];
  __shared__ bf16 Bs[3][128 * 32];
  const int tid = threadIdx.x;
  const int w = tid >> 6, l = tid & 63;
  const int wr = w >> 1, wc = w & 1;
  const int lr = l & 15, lg = l >> 4;
  const int bm = blockIdx.x, bn = blockIdx.y;
  const int K = 512;
  const int sel = bn >> 2, wn = bn & 3;

  const float* A = (sel == 0) ? x1 : x2;
  const float* B = ((sel == 0) ? Wq : (sel == 1) ? Wk : Wv) + (size_t)wn * 128 * K;

  const int c_row = l >> 2;         // row in 16-row chunk
  const int c_s = l & 3;            // 8-f32 slot
  const int sw = (c_s ^ (c_row & 3)) * 8;  // swizzled LDS col (write side)

  // 2 register sets (compile-time indexed), each: 2 chunks x 2 float4 for A and B
  float4 ra0[2][2], ra1[2][2], rb0[2][2], rb1[2][2];

#define ISSUE(t, ra, rb)                                                          \
  {                                                                               \
    _Pragma("unroll") for (int i = 0; i < 2; i++) {                               \
      const int q = w + i * 4;                                                    \
      const float* pa = A + (size_t)(bm * 128 + q * 16 + c_row) * K + (t) * 32 + c_s * 8; \
      ra[i][0] = *reinterpret_cast<const float4*>(pa);                            \
      ra[i][1] = *reinterpret_cast<const float4*>(pa + 4);                        \
      const float* pb = B + (size_t)(q * 16 + c_row) * K + (t) * 32 + c_s * 8;    \
      rb[i][0] = *reinterpret_cast<const float4*>(pb);                            \
      rb[i][1] = *reinterpret_cast<const float4*>(pb + 4);                        \
    }                                                                             \
  }
#define COMMIT(bb, ra, rb)                                                        \
  {                                                                               \
    _Pragma("unroll") for (int i = 0; i < 2; i++) {                               \
      const int q = w + i * 4;                                                    \
      *reinterpret_cast<bf16x8*>(&As[bb][q * 512 + c_row * 32 + sw]) = cvt8(ra[i][0], ra[i][1]); \
      *reinterpret_cast<bf16x8*>(&Bs[bb][q * 512 + c_row * 32 + sw]) = cvt8(rb[i][0], rb[i][1]); \
    }                                                                             \
  }

  f32x4 acc[4][4] = {};
  const int swz = (lr & 3) * 8;

  auto compute = [&](int cur) {
    bf16x8 a[4], b[4];
#pragma unroll
    for (int mi = 0; mi < 4; mi++)
      a[mi] = *reinterpret_cast<const bf16x8*>(
          &As[cur][(wr * 64 + mi * 16 + lr) * 32 + (lg * 8 ^ swz)]);
#pragma unroll
    for (int ni = 0; ni < 4; ni++)
      b[ni] = *reinterpret_cast<const bf16x8*>(
          &Bs[cur][(wc * 64 + ni * 16 + lr) * 32 + (lg * 8 ^ swz)]);
#pragma unroll
    for (int mi = 0; mi < 4; mi++)
#pragma unroll
      for (int ni = 0; ni < 4; ni++)
        acc[mi][ni] = MFMA16x16x32(a[mi], b[ni], acc[mi][ni]);
  };

  ISSUE(0, ra0, rb0);
  ISSUE(1, ra1, rb1);
  asm volatile("s_waitcnt vmcnt(8)" ::: "memory");  // tile0 landed
  COMMIT(0, ra0, rb0);
  asm volatile("s_waitcnt lgkmcnt(0)" ::: "memory");
  SBAR();

  const int NT = 16;
  for (int t = 0; t < NT; t += 2) {
    // ---- even iter t: buf t%3; issue t+2 into set0 ----
    if (t + 2 < NT) ISSUE(t + 2, ra0, rb0);
    compute(t % 3);
    {
      if (t + 2 < NT) asm volatile("s_waitcnt vmcnt(8)" ::: "memory");
      else            asm volatile("s_waitcnt vmcnt(0)" ::: "memory");
      COMMIT((t + 1) % 3, ra1, rb1);  // tile t+1 (set1)
      asm volatile("s_waitcnt lgkmcnt(0)" ::: "memory");
      SBAR();
    }
    // ---- odd iter t+1: buf (t+1)%3; issue t+3 into set1 ----
    if (t + 3 < NT) ISSUE(t + 3, ra1, rb1);
    compute((t + 1) % 3);
    if (t + 2 < NT) {
      if (t + 3 < NT) asm volatile("s_waitcnt vmcnt(8)" ::: "memory");
      else            asm volatile("s_waitcnt vmcnt(0)" ::: "memory");
      COMMIT((t + 2) % 3, ra0, rb0);  // tile t+2 (set0)
      asm volatile("s_waitcnt lgkmcnt(0)" ::: "memory");
      SBAR();
    }
  }
#undef ISSUE
#undef COMMIT

  // epilogue: C/D col=lane&15, row=(lane>>4)*4+reg
  const float scale = (sel == 0) ? 0.18033688011112f : 1.0f;
#pragma unroll
  for (int mi = 0; mi < 4; mi++) {
    const int m0 = bm * 128 + wr * 64 + mi * 16 + lg * 4;
#pragma unroll
    for (int ni = 0; ni < 4; ni++) {
      const int gn = wn * 128 + wc * 64 + ni * 16 + lr;  // h*64+d
      if (sel < 2) {
        bf16* dst = (sel == 0) ? Qw : Kw;
#pragma unroll
        for (int r = 0; r < 4; r++) {
          const int m = m0 + r;
          size_t d = (size_t)((m >> 11) * 8 + (gn >> 6)) * 131072 + (size_t)(m & 2047) * 64 + (gn & 63);
          dst[d] = (bf16)(acc[mi][ni][r] * scale);
        }
      } else {
        bf16x4 pv;
#pragma unroll
        for (int r = 0; r < 4; r++) pv[r] = (bf16)acc[mi][ni][r];
        size_t base = ((size_t)(m0 >> 11) * 512 + gn) * 2048 + (m0 & 2047);
        *reinterpret_cast<bf16x4*>(Vtw + base) = pv;
      }
    }
  }
}

// ---------------- out projection (unchanged, validated) ----------------
__global__ __launch_bounds__(256, 4) void outproj_kernel(
    const bf16* __restrict__ A0, const float* __restrict__ W0,
    float* __restrict__ C0, const float* __restrict__ bias) {
  __shared__ bf16 As[3][128 * 32];
  __shared__ bf16 Bs[2][64 * 32];
  const int tid = threadIdx.x;
  const int w = tid >> 6, l = tid & 63;
  const int wr = w >> 1, wc = w & 1;
  const int lr = l & 15, lg = l >> 4;
  const int bm = blockIdx.x, bn = blockIdx.y;
  const int K = 512;

  const float* Bf = W0 + (size_t)bn * 64 * K;
  const int c_row = l >> 2;
  const int c_s = l & 3;
  const int sw = (c_s ^ (c_row & 3)) * 8;

  float4 lb[2][2];
  auto issue_A = [&](int t, int bb) {
#pragma unroll
    for (int i = 0; i < 2; i++) {
      const int q = w + i * 4;
      gload_lds16(A0 + (size_t)(bm * 128 + q * 16 + c_row) * K + t * 32 + sw, &As[bb][q * 512]);
    }
  };
  auto issue_B = [&](int t, int s) {
    const float* pb = Bf + (size_t)(w * 16 + c_row) * K + t * 32 + c_s * 8;
    lb[s][0] = *reinterpret_cast<const float4*>(pb);
    lb[s][1] = *reinterpret_cast<const float4*>(pb + 4);
  };
  auto commit_B = [&](int s, int bb) {
    *reinterpret_cast<bf16x8*>(&Bs[bb][w * 512 + c_row * 32 + sw]) = cvt8(lb[s][0], lb[s][1]);
  };

  f32x4 acc[4][2] = {};
  const int swz = (lr & 3) * 8;

  issue_A(0, 0); issue_B(0, 0);
  issue_A(1, 1); issue_B(1, 1);
  asm volatile("s_waitcnt vmcnt(4)" ::: "memory");
  commit_B(0, 0);
  asm volatile("s_waitcnt lgkmcnt(0)" ::: "memory");
  SBAR();

  const int NT = 16;
  for (int t = 0; t < NT; t++) {
    if (t + 2 < NT) { issue_A(t + 2, (t + 2) % 3); issue_B(t + 2, t & 1); }

    bf16x8 a[4], b[2];
    const int cur = t % 3;
#pragma unroll
    for (int mi = 0; mi < 4; mi++)
      a[mi] = *reinterpret_cast<const bf16x8*>(
          &As[cur][(wr * 64 + mi * 16 + lr) * 32 + (lg * 8 ^ swz)]);
#pragma unroll
    for (int ni = 0; ni < 2; ni++)
      b[ni] = *reinterpret_cast<const bf16x8*>(
          &Bs[t & 1][(wc * 32 + ni * 16 + lr) * 32 + (lg * 8 ^ swz)]);
#pragma unroll
    for (int mi = 0; mi < 4; mi++)
#pragma unroll
      for (int ni = 0; ni < 2; ni++)
        acc[mi][ni] = MFMA16x16x32(a[mi], b[ni], acc[mi][ni]);

    if (t + 1 < NT) {
      if (t + 2 < NT) asm volatile("s_waitcnt vmcnt(4)" ::: "memory");
      else            asm volatile("s_waitcnt vmcnt(0)" ::: "memory");
      commit_B((t + 1) & 1, (t + 1) & 1);
      asm volatile("s_waitcnt lgkmcnt(0)" ::: "memory");
      SBAR();
    }
  }

#pragma unroll
  for (int mi = 0; mi < 4; mi++) {
    const int m0 = bm * 128 + wr * 64 + mi * 16 + lg * 4;
#pragma unroll
    for (int ni = 0; ni < 2; ni++) {
      const int gn = bn * 64 + wc * 32 + ni * 16 + lr;
      const float bv = bias[gn];
#pragma unroll
      for (int r = 0; r < 4; r++)
        C0[(size_t)(m0 + r) * 512 + gn] = acc[mi][ni][r] + bv;
    }
  }
}

// ---------------- flash attention (r14 structure + T5 setprio) ----------------
__global__ __launch_bounds__(512, 1) void attn_kernel(
    const bf16* __restrict__ Q, const bf16* __restrict__ Kk,
    const bf16* __restrict__ Vt, bf16* __restrict__ AO) {
  __shared__ bf16 KV[2][2][64 * 64];  // [K|V][ring][tile] = 32KB
  __shared__ float cls[4][2][32];     // lsum combine

  const int tid = threadIdx.x;
  const int w = tid >> 6, l = tid & 63;  // w 0..7
  const int q32 = l & 31;
  const int h = l >> 5;
  const int qg = w >> 1, kvh = w & 1;

  const int lin = blockIdx.x;
  const int xcd = lin & 7;
  const int m = lin >> 3;            // 0..31
  const int bh = xcd * 4 + (m & 3);
  const int qb = m >> 2;             // 0..7
  const int b = bh >> 3, hd = bh & 7;

  const bf16* Qb = Q + (size_t)bh * 131072;
  const bf16* Kb = Kk + (size_t)bh * 131072;
  const bf16* Vb = Vt + (size_t)bh * 131072;

  const int q0 = qb * 256 + qg * 64;

  bf16x8 qf[2][4];
#pragma unroll
  for (int i = 0; i < 2; i++)
#pragma unroll
    for (int ks = 0; ks < 4; ks++)
      qf[i][ks] = *reinterpret_cast<const bf16x8*>(
          Qb + (size_t)(q0 + i * 32 + q32) * 64 + ks * 16 + h * 8);

  const int crow = l >> 3;
  const int scol = ((l & 7) ^ crow) * 8;
  auto stage = [&](int kv0, int bb) {
    const int row = w * 8 + crow;
    gload_lds16(Kb + (size_t)(kv0 + row) * 64 + scol, &KV[0][bb][w * 512]);
    gload_lds16(Vb + (size_t)row * 2048 + kv0 + scol, &KV[1][bb][w * 512]);
  };

  f32x16 oacc[2][2] = {};  // [i][db]
  float lsum[2] = {0.f, 0.f};
  const int l7 = l & 7;

  stage(0, 0);
  asm volatile("s_waitcnt vmcnt(0)" ::: "memory");
  SBAR();

  for (int t = 0; t < 32; t++) {
    const int cur = t & 1;
    if (t < 31) stage((t + 1) * 64, cur ^ 1);

    __builtin_amdgcn_s_setprio(1);

    bf16x8 kb[4];
#pragma unroll
    for (int ks = 0; ks < 4; ks++)
      kb[ks] = *reinterpret_cast<const bf16x8*>(
          &KV[0][cur][(kvh * 32 + q32) * 64 + (((ks * 2 + h) ^ l7) * 8)]);

    bf16x8 pa[2][2];
#pragma unroll
    for (int i = 0; i < 2; i++) {
      f32x16 st = {};
#pragma unroll
      for (int ks = 0; ks < 4; ks++)
        st = MFMA32x32x16(kb[ks], qf[i][ks], st);

      float e[16];
#pragma unroll
      for (int r = 0; r < 16; r++) {
        e[r] = fexp2(st[r]);
        lsum[i] += e[r];
      }
      uint32_t Qp[8];
#pragma unroll
      for (int p = 0; p < 8; p++) Qp[p] = cvtpk(e[2 * p], e[2 * p + 1]);
      plswap(Qp[0], Qp[2]);
      plswap(Qp[1], Qp[3]);
      plswap(Qp[4], Qp[6]);
      plswap(Qp[5], Qp[7]);
      pa[i][0] = __builtin_bit_cast(bf16x8, (u32x4){Qp[0], Qp[1], Qp[2], Qp[3]});
      pa[i][1] = __builtin_bit_cast(bf16x8, (u32x4){Qp[4], Qp[5], Qp[6], Qp[7]});
    }

    bf16x8 vb[2][2];
#pragma unroll
    for (int kst = 0; kst < 2; kst++)
#pragma unroll
      for (int db = 0; db < 2; db++)
        vb[kst][db] = *reinterpret_cast<const bf16x8*>(
            &KV[1][cur][(db * 32 + q32) * 64 + (((kvh * 4 + kst * 2 + h) ^ l7) * 8)]);

#pragma unroll
    for (int i = 0; i < 2; i++)
#pragma unroll
      for (int kst = 0; kst < 2; kst++)
#pragma unroll
        for (int db = 0; db < 2; db++)
          oacc[i][db] = MFMA32x32x16(pa[i][kst], vb[kst][db], oacc[i][db]);

    __builtin_amdgcn_s_setprio(0);

    if (t < 31) {
      asm volatile("s_waitcnt vmcnt(0) lgkmcnt(0)" ::: "memory");
      SBAR();
    }
  }

#pragma unroll
  for (int i = 0; i < 2; i++) lsum[i] += __shfl_xor(lsum[i], 32);

  float* cb = (float*)&KV[0][0][0];
  __syncthreads();
  if (kvh == 1 && l < 32) {
    cls[qg][0][q32] = lsum[0];
    cls[qg][1][q32] = lsum[1];
  }
#pragma unroll
  for (int i = 0; i < 2; i++) {
    if (kvh == 1) {
#pragma unroll
      for (int db = 0; db < 2; db++)
#pragma unroll
        for (int r = 0; r < 16; r++)
          cb[((qg * 2 + db) * 16 + r) * 64 + l] = oacc[i][db][r];
    }
    __syncthreads();
    if (kvh == 0) {
#pragma unroll
      for (int db = 0; db < 2; db++)
#pragma unroll
        for (int r = 0; r < 16; r++)
          oacc[i][db][r] += cb[((qg * 2 + db) * 16 + r) * 64 + l];
    }
    __syncthreads();
  }

  if (kvh == 0) {
#pragma unroll
    for (int i = 0; i < 2; i++) {
      lsum[i] += cls[qg][i][q32];
      float inv[16];
#pragma unroll
      for (int r = 0; r < 16; r++) {
        const int qv = (r & 3) + 8 * (r >> 2) + 4 * h;
        inv[r] = 1.f / __shfl(lsum[i], qv);
      }
#pragma unroll
      for (int db = 0; db < 2; db++) {
#pragma unroll
        for (int r = 0; r < 16; r++) {
          const int qv = (r & 3) + 8 * (r >> 2) + 4 * h;
          AO[(size_t)(b * 2048 + q0 + i * 32 + qv) * 512 + hd * 64 + db * 32 + q32] =
              (bf16)(oacc[i][db][r] * inv[r]);
        }
      }
    }
  }
}

// ---------------- launch ----------------
extern "C" void kernel_launch(void* const* d_in, const int* in_sizes, int n_in,
                              void* d_out, int out_size, void* d_ws, size_t ws_size,
                              hipStream_t stream) {
  (void)in_sizes; (void)n_in; (void)out_size; (void)ws_size;
  const float* x1 = (const float*)d_in[0];
  const float* x2 = (const float*)d_in[1];
  const float* Wq = (const float*)d_in[2];
  const float* Wk = (const float*)d_in[3];
  const float* Wv = (const float*)d_in[4];
  const float* Wo = (const float*)d_in[5];
  const float* bo = (const float*)d_in[6];

  uint8_t* ws = (uint8_t*)d_ws;
  bf16* AO  = (bf16*)(ws + 0);          // [8192][512]
  bf16* Qws = (bf16*)(ws + 18874368);   // [b][h][s][64]
  bf16* Kws = (bf16*)(ws + 27262976);   // [b][h][s][64]
  bf16* Vtw = (bf16*)(ws + 35651584);   // [b][h][64][s]

  // Q|K|V fused projection with fused f32->bf16 cast (no separate cast kernel)
  qkv128_kernel<<<dim3(64, 12), 256, 0, stream>>>(x1, x2, Wq, Wk, Wv, Qws, Kws, Vtw);

  attn_kernel<<<256, 512, 0, stream>>>(Qws, Kws, Vtw, AO);

  outproj_kernel<<<dim3(64, 8), 256, 0, stream>>>(AO, Wo, (float*)d_out, bo);
}

// Round 18
// 94.663 us; speedup vs baseline: 1.0929x; 1.0219x over previous
//
#include <hip/hip_runtime.h>
#include <stdint.h>

typedef __bf16 bf16;
typedef __bf16 bf16x8 __attribute__((ext_vector_type(8)));
typedef __bf16 bf16x4 __attribute__((ext_vector_type(4)));
typedef float f32x4 __attribute__((ext_vector_type(4)));
typedef float f32x16 __attribute__((ext_vector_type(16)));
typedef uint32_t u32x4 __attribute__((ext_vector_type(4)));

#define MFMA16x16x32(A, B, C) __builtin_amdgcn_mfma_f32_16x16x32_bf16((A), (B), (C), 0, 0, 0)
#define MFMA32x32x16(A, B, C) __builtin_amdgcn_mfma_f32_32x32x16_bf16((A), (B), (C), 0, 0, 0)
#define SBAR() do { __builtin_amdgcn_s_barrier(); __builtin_amdgcn_sched_barrier(0); } while (0)

__device__ __forceinline__ void gload_lds16(const void* g, void* l) {
  __builtin_amdgcn_global_load_lds((const __attribute__((address_space(1))) void*)g,
                                   (__attribute__((address_space(3))) void*)l,
                                   16, 0, 0);
}

__device__ __forceinline__ float fexp2(float x) { return __builtin_amdgcn_exp2f(x); }

__device__ __forceinline__ uint32_t cvtpk(float a, float b) {
  uint32_t r;
  asm("v_cvt_pk_bf16_f32 %0, %1, %2" : "=v"(r) : "v"(a), "v"(b));
  return r;
}
__device__ __forceinline__ void plswap(uint32_t& a, uint32_t& b) {
  asm volatile("v_permlane32_swap_b32 %0, %1" : "+v"(a), "+v"(b));
}

__device__ __forceinline__ bf16x8 cvt8(float4 a, float4 b) {
  bf16x8 o;
  o[0] = (bf16)a.x; o[1] = (bf16)a.y; o[2] = (bf16)a.z; o[3] = (bf16)a.w;
  o[4] = (bf16)b.x; o[5] = (bf16)b.y; o[6] = (bf16)b.z; o[7] = (bf16)b.w;
  return o;
}

// ---------------- QKV projection with FUSED f32->bf16 cast (validated r15) ----------
__global__ __launch_bounds__(256, 2) void qkv128_kernel(
    const float* __restrict__ x1, const float* __restrict__ x2,
    const float* __restrict__ Wq, const float* __restrict__ Wk,
    const float* __restrict__ Wv, bf16* __restrict__ Qw,
    bf16* __restrict__ Kw, bf16* __restrict__ Vtw) {
  __shared__ bf16 As[3][128 * 32];
  __shared__ bf16 Bs[3][128 * 32];
  const int tid = threadIdx.x;
  const int w = tid >> 6, l = tid & 63;
  const int wr = w >> 1, wc = w & 1;
  const int lr = l & 15, lg = l >> 4;
  const int bm = blockIdx.x, bn = blockIdx.y;
  const int K = 512;
  const int sel = bn >> 2, wn = bn & 3;

  const float* A = (sel == 0) ? x1 : x2;
  const float* B = ((sel == 0) ? Wq : (sel == 1) ? Wk : Wv) + (size_t)wn * 128 * K;

  const int c_row = l >> 2;
  const int c_s = l & 3;
  const int sw = (c_s ^ (c_row & 3)) * 8;

  float4 ra0[2][2], ra1[2][2], rb0[2][2], rb1[2][2];

#define ISSUE(t, ra, rb)                                                          \
  {                                                                               \
    _Pragma("unroll") for (int i = 0; i < 2; i++) {                               \
      const int q = w + i * 4;                                                    \
      const float* pa = A + (size_t)(bm * 128 + q * 16 + c_row) * K + (t) * 32 + c_s * 8; \
      ra[i][0] = *reinterpret_cast<const float4*>(pa);                            \
      ra[i][1] = *reinterpret_cast<const float4*>(pa + 4);                        \
      const float* pb = B + (size_t)(q * 16 + c_row) * K + (t) * 32 + c_s * 8;    \
      rb[i][0] = *reinterpret_cast<const float4*>(pb);                            \
      rb[i][1] = *reinterpret_cast<const float4*>(pb + 4);                        \
    }                                                                             \
  }
#define COMMIT(bb, ra, rb)                                                        \
  {                                                                               \
    _Pragma("unroll") for (int i = 0; i < 2; i++) {                               \
      const int q = w + i * 4;                                                    \
      *reinterpret_cast<bf16x8*>(&As[bb][q * 512 + c_row * 32 + sw]) = cvt8(ra[i][0], ra[i][1]); \
      *reinterpret_cast<bf16x8*>(&Bs[bb][q * 512 + c_row * 32 + sw]) = cvt8(rb[i][0], rb[i][1]); \
    }                                                                             \
  }

  f32x4 acc[4][4] = {};
  const int swz = (lr & 3) * 8;

  auto compute = [&](int cur) {
    bf16x8 a[4], b[4];
#pragma unroll
    for (int mi = 0; mi < 4; mi++)
      a[mi] = *reinterpret_cast<const bf16x8*>(
          &As[cur][(wr * 64 + mi * 16 + lr) * 32 + (lg * 8 ^ swz)]);
#pragma unroll
    for (int ni = 0; ni < 4; ni++)
      b[ni] = *reinterpret_cast<const bf16x8*>(
          &Bs[cur][(wc * 64 + ni * 16 + lr) * 32 + (lg * 8 ^ swz)]);
#pragma unroll
    for (int mi = 0; mi < 4; mi++)
#pragma unroll
      for (int ni = 0; ni < 4; ni++)
        acc[mi][ni] = MFMA16x16x32(a[mi], b[ni], acc[mi][ni]);
  };

  ISSUE(0, ra0, rb0);
  ISSUE(1, ra1, rb1);
  asm volatile("s_waitcnt vmcnt(8)" ::: "memory");
  COMMIT(0, ra0, rb0);
  asm volatile("s_waitcnt lgkmcnt(0)" ::: "memory");
  SBAR();

  const int NT = 16;
  for (int t = 0; t < NT; t += 2) {
    if (t + 2 < NT) ISSUE(t + 2, ra0, rb0);
    compute(t % 3);
    {
      if (t + 2 < NT) asm volatile("s_waitcnt vmcnt(8)" ::: "memory");
      else            asm volatile("s_waitcnt vmcnt(0)" ::: "memory");
      COMMIT((t + 1) % 3, ra1, rb1);
      asm volatile("s_waitcnt lgkmcnt(0)" ::: "memory");
      SBAR();
    }
    if (t + 3 < NT) ISSUE(t + 3, ra1, rb1);
    compute((t + 1) % 3);
    if (t + 2 < NT) {
      if (t + 3 < NT) asm volatile("s_waitcnt vmcnt(8)" ::: "memory");
      else            asm volatile("s_waitcnt vmcnt(0)" ::: "memory");
      COMMIT((t + 2) % 3, ra0, rb0);
      asm volatile("s_waitcnt lgkmcnt(0)" ::: "memory");
      SBAR();
    }
  }
#undef ISSUE
#undef COMMIT

  const float scale = (sel == 0) ? 0.18033688011112f : 1.0f;
#pragma unroll
  for (int mi = 0; mi < 4; mi++) {
    const int m0 = bm * 128 + wr * 64 + mi * 16 + lg * 4;
#pragma unroll
    for (int ni = 0; ni < 4; ni++) {
      const int gn = wn * 128 + wc * 64 + ni * 16 + lr;
      if (sel < 2) {
        bf16* dst = (sel == 0) ? Qw : Kw;
#pragma unroll
        for (int r = 0; r < 4; r++) {
          const int m = m0 + r;
          size_t d = (size_t)((m >> 11) * 8 + (gn >> 6)) * 131072 + (size_t)(m & 2047) * 64 + (gn & 63);
          dst[d] = (bf16)(acc[mi][ni][r] * scale);
        }
      } else {
        bf16x4 pv;
#pragma unroll
        for (int r = 0; r < 4; r++) pv[r] = (bf16)acc[mi][ni][r];
        size_t base = ((size_t)(m0 >> 11) * 512 + gn) * 2048 + (m0 & 2047);
        *reinterpret_cast<bf16x4*>(Vtw + base) = pv;
      }
    }
  }
}

// ---------------- out projection (validated) ----------------
__global__ __launch_bounds__(256, 4) void outproj_kernel(
    const bf16* __restrict__ A0, const float* __restrict__ W0,
    float* __restrict__ C0, const float* __restrict__ bias) {
  __shared__ bf16 As[3][128 * 32];
  __shared__ bf16 Bs[2][64 * 32];
  const int tid = threadIdx.x;
  const int w = tid >> 6, l = tid & 63;
  const int wr = w >> 1, wc = w & 1;
  const int lr = l & 15, lg = l >> 4;
  const int bm = blockIdx.x, bn = blockIdx.y;
  const int K = 512;

  const float* Bf = W0 + (size_t)bn * 64 * K;
  const int c_row = l >> 2;
  const int c_s = l & 3;
  const int sw = (c_s ^ (c_row & 3)) * 8;

  float4 lb[2][2];
  auto issue_A = [&](int t, int bb) {
#pragma unroll
    for (int i = 0; i < 2; i++) {
      const int q = w + i * 4;
      gload_lds16(A0 + (size_t)(bm * 128 + q * 16 + c_row) * K + t * 32 + sw, &As[bb][q * 512]);
    }
  };
  auto issue_B = [&](int t, int s) {
    const float* pb = Bf + (size_t)(w * 16 + c_row) * K + t * 32 + c_s * 8;
    lb[s][0] = *reinterpret_cast<const float4*>(pb);
    lb[s][1] = *reinterpret_cast<const float4*>(pb + 4);
  };
  auto commit_B = [&](int s, int bb) {
    *reinterpret_cast<bf16x8*>(&Bs[bb][w * 512 + c_row * 32 + sw]) = cvt8(lb[s][0], lb[s][1]);
  };

  f32x4 acc[4][2] = {};
  const int swz = (lr & 3) * 8;

  issue_A(0, 0); issue_B(0, 0);
  issue_A(1, 1); issue_B(1, 1);
  asm volatile("s_waitcnt vmcnt(4)" ::: "memory");
  commit_B(0, 0);
  asm volatile("s_waitcnt lgkmcnt(0)" ::: "memory");
  SBAR();

  const int NT = 16;
  for (int t = 0; t < NT; t++) {
    if (t + 2 < NT) { issue_A(t + 2, (t + 2) % 3); issue_B(t + 2, t & 1); }

    bf16x8 a[4], b[2];
    const int cur = t % 3;
#pragma unroll
    for (int mi = 0; mi < 4; mi++)
      a[mi] = *reinterpret_cast<const bf16x8*>(
          &As[cur][(wr * 64 + mi * 16 + lr) * 32 + (lg * 8 ^ swz)]);
#pragma unroll
    for (int ni = 0; ni < 2; ni++)
      b[ni] = *reinterpret_cast<const bf16x8*>(
          &Bs[t & 1][(wc * 32 + ni * 16 + lr) * 32 + (lg * 8 ^ swz)]);
#pragma unroll
    for (int mi = 0; mi < 4; mi++)
#pragma unroll
      for (int ni = 0; ni < 2; ni++)
        acc[mi][ni] = MFMA16x16x32(a[mi], b[ni], acc[mi][ni]);

    if (t + 1 < NT) {
      if (t + 2 < NT) asm volatile("s_waitcnt vmcnt(4)" ::: "memory");
      else            asm volatile("s_waitcnt vmcnt(0)" ::: "memory");
      commit_B((t + 1) & 1, (t + 1) & 1);
      asm volatile("s_waitcnt lgkmcnt(0)" ::: "memory");
      SBAR();
    }
  }

#pragma unroll
  for (int mi = 0; mi < 4; mi++) {
    const int m0 = bm * 128 + wr * 64 + mi * 16 + lg * 4;
#pragma unroll
    for (int ni = 0; ni < 2; ni++) {
      const int gn = bn * 64 + wc * 32 + ni * 16 + lr;
      const float bv = bias[gn];
#pragma unroll
      for (int r = 0; r < 4; r++)
        C0[(size_t)(m0 + r) * 512 + gn] = acc[mi][ni][r] + bv;
    }
  }
}

// ---------------- flash attention: r14-exact (validated at 51.5us, passing) ----------
// Block: 512 thr = 8 waves = 4 q-groups(64 q) x 2 kv-halves; 256 q/block; grid 256.
// Ring-2, stage(t+1), full vmcnt(0) drain per iter (counted vmcnt in this kernel
// failed correctness twice — r16/r17; suspected scratch traffic aliasing the count).
// No setprio (r15: -3us on this lockstep structure).
__global__ __launch_bounds__(512, 1) void attn_kernel(
    const bf16* __restrict__ Q, const bf16* __restrict__ Kk,
    const bf16* __restrict__ Vt, bf16* __restrict__ AO) {
  __shared__ bf16 KV[2][2][64 * 64];  // [K|V][ring][tile] = 32KB
  __shared__ float cls[4][2][32];     // lsum combine

  const int tid = threadIdx.x;
  const int w = tid >> 6, l = tid & 63;  // w 0..7
  const int q32 = l & 31;
  const int h = l >> 5;
  const int qg = w >> 1, kvh = w & 1;

  // XCD-aware decode: grid 256, lin&7 = XCD; 4 bh per XCD -> K/V L2-resident
  const int lin = blockIdx.x;
  const int xcd = lin & 7;
  const int m = lin >> 3;            // 0..31
  const int bh = xcd * 4 + (m & 3);
  const int qb = m >> 2;             // 0..7
  const int b = bh >> 3, hd = bh & 7;

  const bf16* Qb = Q + (size_t)bh * 131072;
  const bf16* Kb = Kk + (size_t)bh * 131072;
  const bf16* Vb = Vt + (size_t)bh * 131072;

  const int q0 = qb * 256 + qg * 64;

  // Q B-frags: sub-block i, col q = q32, k = d = ks*16 + h*8 + j
  bf16x8 qf[2][4];
#pragma unroll
  for (int i = 0; i < 2; i++)
#pragma unroll
    for (int ks = 0; ks < 4; ks++)
      qf[i][ks] = *reinterpret_cast<const bf16x8*>(
          Qb + (size_t)(q0 + i * 32 + q32) * 64 + ks * 16 + h * 8);

  // staging: wave w stages K-chunk w and V-chunk w (8 rows x 64 each, 1KB)
  const int crow = l >> 3;
  const int scol = ((l & 7) ^ crow) * 8;
  auto stage = [&](int kv0, int bb) {
    const int row = w * 8 + crow;
    gload_lds16(Kb + (size_t)(kv0 + row) * 64 + scol, &KV[0][bb][w * 512]);
    gload_lds16(Vb + (size_t)row * 2048 + kv0 + scol, &KV[1][bb][w * 512]);
  };

  f32x16 oacc[2][2] = {};  // [i][db]
  float lsum[2] = {0.f, 0.f};
  const int l7 = l & 7;

  stage(0, 0);
  asm volatile("s_waitcnt vmcnt(0)" ::: "memory");
  SBAR();

  for (int t = 0; t < 32; t++) {
    const int cur = t & 1;
    if (t < 31) stage((t + 1) * 64, cur ^ 1);

    // K A-frags for this kv-half: row kv = kvh*32 + q32 (shared by both q-sub-blocks)
    bf16x8 kb[4];
#pragma unroll
    for (int ks = 0; ks < 4; ks++)
      kb[ks] = *reinterpret_cast<const bf16x8*>(
          &KV[0][cur][(kvh * 32 + q32) * 64 + (((ks * 2 + h) ^ l7) * 8)]);

    bf16x8 pa[2][2];
#pragma unroll
    for (int i = 0; i < 2; i++) {
      // S^T: col = q32 (of sub-block i), row kv_local = (r&3)+8*(r>>2)+4h
      f32x16 st = {};
#pragma unroll
      for (int ks = 0; ks < 4; ks++)
        st = MFMA32x32x16(kb[ks], qf[i][ks], st);

      float e[16];
#pragma unroll
      for (int r = 0; r < 16; r++) {
        e[r] = fexp2(st[r]);
        lsum[i] += e[r];
      }
      uint32_t Qp[8];
#pragma unroll
      for (int p = 0; p < 8; p++) Qp[p] = cvtpk(e[2 * p], e[2 * p + 1]);
      plswap(Qp[0], Qp[2]);
      plswap(Qp[1], Qp[3]);
      plswap(Qp[4], Qp[6]);
      plswap(Qp[5], Qp[7]);
      pa[i][0] = __builtin_bit_cast(bf16x8, (u32x4){Qp[0], Qp[1], Qp[2], Qp[3]});
      pa[i][1] = __builtin_bit_cast(bf16x8, (u32x4){Qp[4], Qp[5], Qp[6], Qp[7]});
    }

    // V B-frags (shared by both q-sub-blocks): rows d = db*32+q32
    bf16x8 vb[2][2];
#pragma unroll
    for (int kst = 0; kst < 2; kst++)
#pragma unroll
      for (int db = 0; db < 2; db++)
        vb[kst][db] = *reinterpret_cast<const bf16x8*>(
            &KV[1][cur][(db * 32 + q32) * 64 + (((kvh * 4 + kst * 2 + h) ^ l7) * 8)]);

    // PV partials
#pragma unroll
    for (int i = 0; i < 2; i++)
#pragma unroll
      for (int kst = 0; kst < 2; kst++)
#pragma unroll
        for (int db = 0; db < 2; db++)
          oacc[i][db] = MFMA32x32x16(pa[i][kst], vb[kst][db], oacc[i][db]);

    if (t < 31) {
      asm volatile("s_waitcnt vmcnt(0) lgkmcnt(0)" ::: "memory");
      SBAR();
    }
  }

  // lanes l and l+32 hold partials of the same q (within this wave's kv-half)
#pragma unroll
  for (int i = 0; i < 2; i++) lsum[i] += __shfl_xor(lsum[i], 32);

  // combine kv-halves via dead K/V LDS (8192 f32 = 32KB), two passes (i=0, i=1)
  float* cb = (float*)&KV[0][0][0];
  __syncthreads();
  if (kvh == 1 && l < 32) {
    cls[qg][0][q32] = lsum[0];
    cls[qg][1][q32] = lsum[1];
  }
#pragma unroll
  for (int i = 0; i < 2; i++) {
    if (kvh == 1) {
#pragma unroll
      for (int db = 0; db < 2; db++)
#pragma unroll
        for (int r = 0; r < 16; r++)
          cb[((qg * 2 + db) * 16 + r) * 64 + l] = oacc[i][db][r];
    }
    __syncthreads();
    if (kvh == 0) {
#pragma unroll
      for (int db = 0; db < 2; db++)
#pragma unroll
        for (int r = 0; r < 16; r++)
          oacc[i][db][r] += cb[((qg * 2 + db) * 16 + r) * 64 + l];
    }
    __syncthreads();
  }

  if (kvh == 0) {
#pragma unroll
    for (int i = 0; i < 2; i++) {
      lsum[i] += cls[qg][i][q32];
      float inv[16];
#pragma unroll
      for (int r = 0; r < 16; r++) {
        const int qv = (r & 3) + 8 * (r >> 2) + 4 * h;
        inv[r] = 1.f / __shfl(lsum[i], qv);
      }
#pragma unroll
      for (int db = 0; db < 2; db++) {
#pragma unroll
        for (int r = 0; r < 16; r++) {
          const int qv = (r & 3) + 8 * (r >> 2) + 4 * h;
          AO[(size_t)(b * 2048 + q0 + i * 32 + qv) * 512 + hd * 64 + db * 32 + q32] =
              (bf16)(oacc[i][db][r] * inv[r]);
        }
      }
    }
  }
}

// ---------------- launch ----------------
extern "C" void kernel_launch(void* const* d_in, const int* in_sizes, int n_in,
                              void* d_out, int out_size, void* d_ws, size_t ws_size,
                              hipStream_t stream) {
  (void)in_sizes; (void)n_in; (void)out_size; (void)ws_size;
  const float* x1 = (const float*)d_in[0];
  const float* x2 = (const float*)d_in[1];
  const float* Wq = (const float*)d_in[2];
  const float* Wk = (const float*)d_in[3];
  const float* Wv = (const float*)d_in[4];
  const float* Wo = (const float*)d_in[5];
  const float* bo = (const float*)d_in[6];

  uint8_t* ws = (uint8_t*)d_ws;
  bf16* AO  = (bf16*)(ws + 0);          // [8192][512]
  bf16* Qws = (bf16*)(ws + 18874368);   // [b][h][s][64]
  bf16* Kws = (bf16*)(ws + 27262976);   // [b][h][s][64]
  bf16* Vtw = (bf16*)(ws + 35651584);   // [b][h][64][s]

  qkv128_kernel<<<dim3(64, 12), 256, 0, stream>>>(x1, x2, Wq, Wk, Wv, Qws, Kws, Vtw);

  attn_kernel<<<256, 512, 0, stream>>>(Qws, Kws, Vtw, AO);

  outproj_kernel<<<dim3(64, 8), 256, 0, stream>>>(AO, Wo, (float*)d_out, bo);
}

// Round 19
// 92.839 us; speedup vs baseline: 1.1144x; 1.0196x over previous
//
#include <hip/hip_runtime.h>
#include <stdint.h>

typedef __bf16 bf16;
typedef __bf16 bf16x8 __attribute__((ext_vector_type(8)));
typedef __bf16 bf16x4 __attribute__((ext_vector_type(4)));
typedef float f32x4 __attribute__((ext_vector_type(4)));
typedef float f32x16 __attribute__((ext_vector_type(16)));
typedef uint32_t u32x4 __attribute__((ext_vector_type(4)));

#define MFMA16x16x32(A, B, C) __builtin_amdgcn_mfma_f32_16x16x32_bf16((A), (B), (C), 0, 0, 0)
#define MFMA32x32x16(A, B, C) __builtin_amdgcn_mfma_f32_32x32x16_bf16((A), (B), (C), 0, 0, 0)
#define SBAR() do { __builtin_amdgcn_s_barrier(); __builtin_amdgcn_sched_barrier(0); } while (0)

__device__ __forceinline__ void gload_lds16(const void* g, void* l) {
  __builtin_amdgcn_global_load_lds((const __attribute__((address_space(1))) void*)g,
                                   (__attribute__((address_space(3))) void*)l,
                                   16, 0, 0);
}

__device__ __forceinline__ float fexp2(float x) { return __builtin_amdgcn_exp2f(x); }

__device__ __forceinline__ uint32_t cvtpk(float a, float b) {
  uint32_t r;
  asm("v_cvt_pk_bf16_f32 %0, %1, %2" : "=v"(r) : "v"(a), "v"(b));
  return r;
}
__device__ __forceinline__ void plswap(uint32_t& a, uint32_t& b) {
  asm volatile("v_permlane32_swap_b32 %0, %1" : "+v"(a), "+v"(b));
}

__device__ __forceinline__ bf16x8 cvt8(float4 a, float4 b) {
  bf16x8 o;
  o[0] = (bf16)a.x; o[1] = (bf16)a.y; o[2] = (bf16)a.z; o[3] = (bf16)a.w;
  o[4] = (bf16)b.x; o[5] = (bf16)b.y; o[6] = (bf16)b.z; o[7] = (bf16)b.w;
  return o;
}

// ---------------- QKV projection with FUSED f32->bf16 cast (validated r15/r18) -------
__global__ __launch_bounds__(256, 2) void qkv128_kernel(
    const float* __restrict__ x1, const float* __restrict__ x2,
    const float* __restrict__ Wq, const float* __restrict__ Wk,
    const float* __restrict__ Wv, bf16* __restrict__ Qw,
    bf16* __restrict__ Kw, bf16* __restrict__ Vtw) {
  __shared__ bf16 As[3][128 * 32];
  __shared__ bf16 Bs[3][128 * 32];
  const int tid = threadIdx.x;
  const int w = tid >> 6, l = tid & 63;
  const int wr = w >> 1, wc = w & 1;
  const int lr = l & 15, lg = l >> 4;
  const int bm = blockIdx.x, bn = blockIdx.y;
  const int K = 512;
  const int sel = bn >> 2, wn = bn & 3;

  const float* A = (sel == 0) ? x1 : x2;
  const float* B = ((sel == 0) ? Wq : (sel == 1) ? Wk : Wv) + (size_t)wn * 128 * K;

  const int c_row = l >> 2;
  const int c_s = l & 3;
  const int sw = (c_s ^ (c_row & 3)) * 8;

  float4 ra0[2][2], ra1[2][2], rb0[2][2], rb1[2][2];

#define ISSUE(t, ra, rb)                                                          \
  {                                                                               \
    _Pragma("unroll") for (int i = 0; i < 2; i++) {                               \
      const int q = w + i * 4;                                                    \
      const float* pa = A + (size_t)(bm * 128 + q * 16 + c_row) * K + (t) * 32 + c_s * 8; \
      ra[i][0] = *reinterpret_cast<const float4*>(pa);                            \
      ra[i][1] = *reinterpret_cast<const float4*>(pa + 4);                        \
      const float* pb = B + (size_t)(q * 16 + c_row) * K + (t) * 32 + c_s * 8;    \
      rb[i][0] = *reinterpret_cast<const float4*>(pb);                            \
      rb[i][1] = *reinterpret_cast<const float4*>(pb + 4);                        \
    }                                                                             \
  }
#define COMMIT(bb, ra, rb)                                                        \
  {                                                                               \
    _Pragma("unroll") for (int i = 0; i < 2; i++) {                               \
      const int q = w + i * 4;                                                    \
      *reinterpret_cast<bf16x8*>(&As[bb][q * 512 + c_row * 32 + sw]) = cvt8(ra[i][0], ra[i][1]); \
      *reinterpret_cast<bf16x8*>(&Bs[bb][q * 512 + c_row * 32 + sw]) = cvt8(rb[i][0], rb[i][1]); \
    }                                                                             \
  }

  f32x4 acc[4][4] = {};
  const int swz = (lr & 3) * 8;

  auto compute = [&](int cur) {
    bf16x8 a[4], b[4];
#pragma unroll
    for (int mi = 0; mi < 4; mi++)
      a[mi] = *reinterpret_cast<const bf16x8*>(
          &As[cur][(wr * 64 + mi * 16 + lr) * 32 + (lg * 8 ^ swz)]);
#pragma unroll
    for (int ni = 0; ni < 4; ni++)
      b[ni] = *reinterpret_cast<const bf16x8*>(
          &Bs[cur][(wc * 64 + ni * 16 + lr) * 32 + (lg * 8 ^ swz)]);
#pragma unroll
    for (int mi = 0; mi < 4; mi++)
#pragma unroll
      for (int ni = 0; ni < 4; ni++)
        acc[mi][ni] = MFMA16x16x32(a[mi], b[ni], acc[mi][ni]);
  };

  ISSUE(0, ra0, rb0);
  ISSUE(1, ra1, rb1);
  asm volatile("s_waitcnt vmcnt(8)" ::: "memory");
  COMMIT(0, ra0, rb0);
  asm volatile("s_waitcnt lgkmcnt(0)" ::: "memory");
  SBAR();

  const int NT = 16;
  for (int t = 0; t < NT; t += 2) {
    if (t + 2 < NT) ISSUE(t + 2, ra0, rb0);
    compute(t % 3);
    {
      if (t + 2 < NT) asm volatile("s_waitcnt vmcnt(8)" ::: "memory");
      else            asm volatile("s_waitcnt vmcnt(0)" ::: "memory");
      COMMIT((t + 1) % 3, ra1, rb1);
      asm volatile("s_waitcnt lgkmcnt(0)" ::: "memory");
      SBAR();
    }
    if (t + 3 < NT) ISSUE(t + 3, ra1, rb1);
    compute((t + 1) % 3);
    if (t + 2 < NT) {
      if (t + 3 < NT) asm volatile("s_waitcnt vmcnt(8)" ::: "memory");
      else            asm volatile("s_waitcnt vmcnt(0)" ::: "memory");
      COMMIT((t + 2) % 3, ra0, rb0);
      asm volatile("s_waitcnt lgkmcnt(0)" ::: "memory");
      SBAR();
    }
  }
#undef ISSUE
#undef COMMIT

  const float scale = (sel == 0) ? 0.18033688011112f : 1.0f;
#pragma unroll
  for (int mi = 0; mi < 4; mi++) {
    const int m0 = bm * 128 + wr * 64 + mi * 16 + lg * 4;
#pragma unroll
    for (int ni = 0; ni < 4; ni++) {
      const int gn = wn * 128 + wc * 64 + ni * 16 + lr;
      if (sel < 2) {
        bf16* dst = (sel == 0) ? Qw : Kw;
#pragma unroll
        for (int r = 0; r < 4; r++) {
          const int m = m0 + r;
          size_t d = (size_t)((m >> 11) * 8 + (gn >> 6)) * 131072 + (size_t)(m & 2047) * 64 + (gn & 63);
          dst[d] = (bf16)(acc[mi][ni][r] * scale);
        }
      } else {
        bf16x4 pv;
#pragma unroll
        for (int r = 0; r < 4; r++) pv[r] = (bf16)acc[mi][ni][r];
        size_t base = ((size_t)(m0 >> 11) * 512 + gn) * 2048 + (m0 & 2047);
        *reinterpret_cast<bf16x4*>(Vtw + base) = pv;
      }
    }
  }
}

// ---------------- out projection (validated) ----------------
__global__ __launch_bounds__(256, 4) void outproj_kernel(
    const bf16* __restrict__ A0, const float* __restrict__ W0,
    float* __restrict__ C0, const float* __restrict__ bias) {
  __shared__ bf16 As[3][128 * 32];
  __shared__ bf16 Bs[2][64 * 32];
  const int tid = threadIdx.x;
  const int w = tid >> 6, l = tid & 63;
  const int wr = w >> 1, wc = w & 1;
  const int lr = l & 15, lg = l >> 4;
  const int bm = blockIdx.x, bn = blockIdx.y;
  const int K = 512;

  const float* Bf = W0 + (size_t)bn * 64 * K;
  const int c_row = l >> 2;
  const int c_s = l & 3;
  const int sw = (c_s ^ (c_row & 3)) * 8;

  float4 lb[2][2];
  auto issue_A = [&](int t, int bb) {
#pragma unroll
    for (int i = 0; i < 2; i++) {
      const int q = w + i * 4;
      gload_lds16(A0 + (size_t)(bm * 128 + q * 16 + c_row) * K + t * 32 + sw, &As[bb][q * 512]);
    }
  };
  auto issue_B = [&](int t, int s) {
    const float* pb = Bf + (size_t)(w * 16 + c_row) * K + t * 32 + c_s * 8;
    lb[s][0] = *reinterpret_cast<const float4*>(pb);
    lb[s][1] = *reinterpret_cast<const float4*>(pb + 4);
  };
  auto commit_B = [&](int s, int bb) {
    *reinterpret_cast<bf16x8*>(&Bs[bb][w * 512 + c_row * 32 + sw]) = cvt8(lb[s][0], lb[s][1]);
  };

  f32x4 acc[4][2] = {};
  const int swz = (lr & 3) * 8;

  issue_A(0, 0); issue_B(0, 0);
  issue_A(1, 1); issue_B(1, 1);
  asm volatile("s_waitcnt vmcnt(4)" ::: "memory");
  commit_B(0, 0);
  asm volatile("s_waitcnt lgkmcnt(0)" ::: "memory");
  SBAR();

  const int NT = 16;
  for (int t = 0; t < NT; t++) {
    if (t + 2 < NT) { issue_A(t + 2, (t + 2) % 3); issue_B(t + 2, t & 1); }

    bf16x8 a[4], b[2];
    const int cur = t % 3;
#pragma unroll
    for (int mi = 0; mi < 4; mi++)
      a[mi] = *reinterpret_cast<const bf16x8*>(
          &As[cur][(wr * 64 + mi * 16 + lr) * 32 + (lg * 8 ^ swz)]);
#pragma unroll
    for (int ni = 0; ni < 2; ni++)
      b[ni] = *reinterpret_cast<const bf16x8*>(
          &Bs[t & 1][(wc * 32 + ni * 16 + lr) * 32 + (lg * 8 ^ swz)]);
#pragma unroll
    for (int mi = 0; mi < 4; mi++)
#pragma unroll
      for (int ni = 0; ni < 2; ni++)
        acc[mi][ni] = MFMA16x16x32(a[mi], b[ni], acc[mi][ni]);

    if (t + 1 < NT) {
      if (t + 2 < NT) asm volatile("s_waitcnt vmcnt(4)" ::: "memory");
      else            asm volatile("s_waitcnt vmcnt(0)" ::: "memory");
      commit_B((t + 1) & 1, (t + 1) & 1);
      asm volatile("s_waitcnt lgkmcnt(0)" ::: "memory");
      SBAR();
    }
  }

#pragma unroll
  for (int mi = 0; mi < 4; mi++) {
    const int m0 = bm * 128 + wr * 64 + mi * 16 + lg * 4;
#pragma unroll
    for (int ni = 0; ni < 2; ni++) {
      const int gn = bn * 64 + wc * 32 + ni * 16 + lr;
      const float bv = bias[gn];
#pragma unroll
      for (int r = 0; r < 4; r++)
        C0[(size_t)(m0 + r) * 512 + gn] = acc[mi][ni][r] + bv;
    }
  }
}

// ---------------- flash attention: r14 tile x2 per barrier, ring-4, FULL drain -------
// Block: 512 thr = 8 waves = 4 q-groups(64 q) x 2 kv-halves; 256 q/block; grid 256.
// Tilebody/staging/combine byte-identical to r18 (validated). Ring-4, TWO tiles per
// barrier interval, full vmcnt(0) drain before every barrier (no counted-N vmcnt —
// that failed r16/r17). Barrier/drain events: 32 -> 16, each drain hidden under
// two tilebodies.
__global__ __launch_bounds__(512, 1) void attn_kernel(
    const bf16* __restrict__ Q, const bf16* __restrict__ Kk,
    const bf16* __restrict__ Vt, bf16* __restrict__ AO) {
  __shared__ bf16 KV[2][4][64 * 64];  // [K|V][ring4][tile] = 64KB
  __shared__ float cls[4][2][32];     // lsum combine

  const int tid = threadIdx.x;
  const int w = tid >> 6, l = tid & 63;  // w 0..7
  const int q32 = l & 31;
  const int h = l >> 5;
  const int qg = w >> 1, kvh = w & 1;
  const int l7 = l & 7;

  // XCD-aware decode: grid 256, lin&7 = XCD; 4 bh per XCD -> K/V L2-resident
  const int lin = blockIdx.x;
  const int xcd = lin & 7;
  const int m = lin >> 3;            // 0..31
  const int bh = xcd * 4 + (m & 3);
  const int qb = m >> 2;             // 0..7
  const int b = bh >> 3, hd = bh & 7;

  const bf16* Qb = Q + (size_t)bh * 131072;
  const bf16* Kb = Kk + (size_t)bh * 131072;
  const bf16* Vb = Vt + (size_t)bh * 131072;

  const int q0 = qb * 256 + qg * 64;

  // Q B-frags: sub-block i, col q = q32, k = d = ks*16 + h*8 + j
  bf16x8 qf[2][4];
#pragma unroll
  for (int i = 0; i < 2; i++)
#pragma unroll
    for (int ks = 0; ks < 4; ks++)
      qf[i][ks] = *reinterpret_cast<const bf16x8*>(
          Qb + (size_t)(q0 + i * 32 + q32) * 64 + ks * 16 + h * 8);

  // staging: wave w stages K-chunk w and V-chunk w (8 rows x 64 each, 1KB)
  const int crow = l >> 3;
  const int scol = ((l & 7) ^ crow) * 8;
  auto stage = [&](int kv0, int bb) {
    const int row = w * 8 + crow;
    gload_lds16(Kb + (size_t)(kv0 + row) * 64 + scol, &KV[0][bb][w * 512]);
    gload_lds16(Vb + (size_t)row * 2048 + kv0 + scol, &KV[1][bb][w * 512]);
  };

  f32x16 oacc[2][2] = {};  // [i][db]
  float lsum[2] = {0.f, 0.f};

  // per-64kv-tile compute (r14/r18-exact indexing)
  auto tilebody = [&](int cur) {
    bf16x8 kb[4];
#pragma unroll
    for (int ks = 0; ks < 4; ks++)
      kb[ks] = *reinterpret_cast<const bf16x8*>(
          &KV[0][cur][(kvh * 32 + q32) * 64 + (((ks * 2 + h) ^ l7) * 8)]);

    bf16x8 pa[2][2];
#pragma unroll
    for (int i = 0; i < 2; i++) {
      f32x16 st = {};
#pragma unroll
      for (int ks = 0; ks < 4; ks++)
        st = MFMA32x32x16(kb[ks], qf[i][ks], st);

      float e[16];
#pragma unroll
      for (int r = 0; r < 16; r++) {
        e[r] = fexp2(st[r]);
        lsum[i] += e[r];
      }
      uint32_t Qp[8];
#pragma unroll
      for (int p2 = 0; p2 < 8; p2++) Qp[p2] = cvtpk(e[2 * p2], e[2 * p2 + 1]);
      plswap(Qp[0], Qp[2]);
      plswap(Qp[1], Qp[3]);
      plswap(Qp[4], Qp[6]);
      plswap(Qp[5], Qp[7]);
      pa[i][0] = __builtin_bit_cast(bf16x8, (u32x4){Qp[0], Qp[1], Qp[2], Qp[3]});
      pa[i][1] = __builtin_bit_cast(bf16x8, (u32x4){Qp[4], Qp[5], Qp[6], Qp[7]});
    }

    bf16x8 vb[2][2];
#pragma unroll
    for (int kst = 0; kst < 2; kst++)
#pragma unroll
      for (int db = 0; db < 2; db++)
        vb[kst][db] = *reinterpret_cast<const bf16x8*>(
            &KV[1][cur][(db * 32 + q32) * 64 + (((kvh * 4 + kst * 2 + h) ^ l7) * 8)]);

#pragma unroll
    for (int i = 0; i < 2; i++)
#pragma unroll
      for (int kst = 0; kst < 2; kst++)
#pragma unroll
        for (int db = 0; db < 2; db++)
          oacc[i][db] = MFMA32x32x16(pa[i][kst], vb[kst][db], oacc[i][db]);
  };

  // prologue: stage tiles 0,1; full drain
  stage(0, 0);
  stage(64, 1);
  asm volatile("s_waitcnt vmcnt(0)" ::: "memory");
  SBAR();

  for (int p = 0; p < 16; p++) {
    const int t0 = 2 * p, t1 = 2 * p + 1;
    if (p < 15) {
      stage((t0 + 2) * 64, (t0 + 2) & 3);
      stage((t1 + 2) * 64, (t1 + 2) & 3);
    }
    tilebody(t0 & 3);
    tilebody(t1 & 3);
    if (p < 15) {
      asm volatile("s_waitcnt vmcnt(0) lgkmcnt(0)" ::: "memory");
      SBAR();
    }
  }

  // lanes l and l+32 hold partials of the same q (within this wave's kv-half)
#pragma unroll
  for (int i = 0; i < 2; i++) lsum[i] += __shfl_xor(lsum[i], 32);

  // combine kv-halves via dead K/V LDS (first 32KB), two passes (i=0, i=1)
  float* cb = (float*)&KV[0][0][0];
  __syncthreads();
  if (kvh == 1 && l < 32) {
    cls[qg][0][q32] = lsum[0];
    cls[qg][1][q32] = lsum[1];
  }
#pragma unroll
  for (int i = 0; i < 2; i++) {
    if (kvh == 1) {
#pragma unroll
      for (int db = 0; db < 2; db++)
#pragma unroll
        for (int r = 0; r < 16; r++)
          cb[((qg * 2 + db) * 16 + r) * 64 + l] = oacc[i][db][r];
    }
    __syncthreads();
    if (kvh == 0) {
#pragma unroll
      for (int db = 0; db < 2; db++)
#pragma unroll
        for (int r = 0; r < 16; r++)
          oacc[i][db][r] += cb[((qg * 2 + db) * 16 + r) * 64 + l];
    }
    __syncthreads();
  }

  if (kvh == 0) {
#pragma unroll
    for (int i = 0; i < 2; i++) {
      lsum[i] += cls[qg][i][q32];
      float inv[16];
#pragma unroll
      for (int r = 0; r < 16; r++) {
        const int qv = (r & 3) + 8 * (r >> 2) + 4 * h;
        inv[r] = 1.f / __shfl(lsum[i], qv);
      }
#pragma unroll
      for (int db = 0; db < 2; db++) {
#pragma unroll
        for (int r = 0; r < 16; r++) {
          const int qv = (r & 3) + 8 * (r >> 2) + 4 * h;
          AO[(size_t)(b * 2048 + q0 + i * 32 + qv) * 512 + hd * 64 + db * 32 + q32] =
              (bf16)(oacc[i][db][r] * inv[r]);
        }
      }
    }
  }
}

// ---------------- launch ----------------
extern "C" void kernel_launch(void* const* d_in, const int* in_sizes, int n_in,
                              void* d_out, int out_size, void* d_ws, size_t ws_size,
                              hipStream_t stream) {
  (void)in_sizes; (void)n_in; (void)out_size; (void)ws_size;
  const float* x1 = (const float*)d_in[0];
  const float* x2 = (const float*)d_in[1];
  const float* Wq = (const float*)d_in[2];
  const float* Wk = (const float*)d_in[3];
  const float* Wv = (const float*)d_in[4];
  const float* Wo = (const float*)d_in[5];
  const float* bo = (const float*)d_in[6];

  uint8_t* ws = (uint8_t*)d_ws;
  bf16* AO  = (bf16*)(ws + 0);          // [8192][512]
  bf16* Qws = (bf16*)(ws + 18874368);   // [b][h][s][64]
  bf16* Kws = (bf16*)(ws + 27262976);   // [b][h][s][64]
  bf16* Vtw = (bf16*)(ws + 35651584);   // [b][h][64][s]

  qkv128_kernel<<<dim3(64, 12), 256, 0, stream>>>(x1, x2, Wq, Wk, Wv, Qws, Kws, Vtw);

  attn_kernel<<<256, 512, 0, stream>>>(Qws, Kws, Vtw, AO);

  outproj_kernel<<<dim3(64, 8), 256, 0, stream>>>(AO, Wo, (float*)d_out, bo);
}